// Round 14
// baseline (554.274 us; speedup 1.0000x reference)
//
#include <hip/hip_runtime.h>
#include <math.h>

constexpr int cNS = 64, cNV = 32, cNB = 8, cL = 4, cEMB = 32, cNT = 10;
constexpr float PI_F = 3.14159265358979323846f;
constexpr float INV_SQRT_NN = 0.17677669529663687f;   // 1/sqrt(32)
constexpr float BESSEL_C = 2.3094010767585034f;       // sqrt(2/3)*sqrt(8)
constexpr float SQRT3 = 1.7320508075688772f;

// wb row stride in u16: 196 (98 dwords, 98 % 32 = 2 -> good bank spread).
// Swizzled cols stay < 192 <= 196; f-region at 4992..6272 (above hid region 0..2304).
constexpr int WST = 196;
constexpr int FOFF = 4992;

typedef unsigned short u16;
typedef unsigned int u32;
typedef unsigned long long u64;
typedef __attribute__((ext_vector_type(8))) short bf16x8;
typedef __attribute__((ext_vector_type(4))) float f32x4;
typedef __attribute__((ext_vector_type(2))) float f32x2;
typedef __attribute__((ext_vector_type(4))) int i32x4;

__device__ __forceinline__ u16 f2b(float x) {   // f32 -> bf16 RNE (scalar fallback)
  u32 u = __float_as_uint(x);
  return (u16)((u + 0x7fffu + ((u >> 16) & 1u)) >> 16);
}
__device__ __forceinline__ float b2f(u16 h) { return __uint_as_float(((u32)h) << 16); }
__device__ __forceinline__ float blo(u32 w) { return __uint_as_float(w << 16); }
__device__ __forceinline__ float bhi(u32 w) { return __uint_as_float(w & 0xffff0000u); }

// HW packed f32->bf16 (2 values, 1 instruction)
__device__ __forceinline__ u32 pkbf(float lo, float hi) {
  u32 r;
  asm("v_cvt_pk_bf16_f32 %0, %1, %2" : "=v"(r) : "v"(lo), "v"(hi));
  return r;
}

// lgkmcnt(0) + hard scheduling fence (rule #18)
__device__ __forceinline__ void lds_fence() {
  asm volatile("s_waitcnt lgkmcnt(0)" ::: "memory");
  __builtin_amdgcn_sched_barrier(0);
}

union U8 { bf16x8 v; u32 w[4]; };

__device__ __forceinline__ f32x4 mfma16(bf16x8 a, bf16x8 b, f32x4 c) {
  return __builtin_amdgcn_mfma_f32_16x16x32_bf16(a, b, c, 0, 0, 0);
}

// ---------------- precompute kernels ----------------

__global__ void k_precompA(const float* __restrict__ emb, const float* __restrict__ Wss,
                           float* __restrict__ A) {
  int idx = blockIdx.x * 256 + threadIdx.x;
  if (idx >= cL * cNT * 64 * 96) return;
  int m = idx % 96;
  int u = (idx / 96) % 64;
  int t = (idx / (96 * 64)) % cNT;
  int l = idx / (96 * 64 * cNT);
  float acc = 0.f;
#pragma unroll
  for (int e = 0; e < 32; ++e)
    acc += emb[t * 32 + e] * Wss[((size_t)(l * 64 + u) * 32 + e) * 96 + m];
  A[idx] = acc;
}

__global__ void k_precompB(const float* __restrict__ emb, const float* __restrict__ Wsv_,
                           float* __restrict__ B) {
  int idx = blockIdx.x * 256 + threadIdx.x;
  if (idx >= cL * cNT * 32 * 32) return;
  int vo = idx % 32;
  int u = (idx / 32) % 32;
  int t = (idx / 1024) % cNT;
  int l = idx / (1024 * cNT);
  float acc = 0.f;
#pragma unroll
  for (int e = 0; e < 32; ++e)
    acc += emb[t * 32 + e] * Wsv_[((size_t)(l * 32 + u) * 32 + e) * 32 + vo];
  B[idx] = acc;
}

// pack fc2 / W_sv / W_vs / fc1 into bf16 MFMA-B layouts: BL[(k/8)*N*8 + n*8 + (k%8)]
__global__ void k_packB(const float* __restrict__ fc2, const float* __restrict__ Wsv,
                        const float* __restrict__ Wvs, const float* __restrict__ fc1,
                        u16* __restrict__ fc2L, u16* __restrict__ WsvL,
                        u16* __restrict__ WvsL, u16* __restrict__ fc1L) {
  int idx = blockIdx.x * 256 + threadIdx.x;
  const int T1 = cL * 12288, T2 = cL * 2 * 2048, T3 = cL * 2 * 3072, T4 = cL * 2048;
  if (idx < T1) {
    int l = idx / 12288, r = idx % 12288;
    int ki = r & 7, tt = r >> 3;
    int nn = tt % 192, kq = tt / 192;
    fc2L[idx] = f2b(fc2[((size_t)(l * 64) + kq * 8 + ki) * 192 + nn]);
  } else if (idx < T1 + T2) {
    int r0 = idx - T1;
    int l = r0 / 4096, r1 = r0 % 4096;
    int k2 = r1 / 2048, r = r1 % 2048;
    int ki = r & 7, tt = r >> 3;
    int mm = tt % 32, kq = tt / 32;
    WsvL[r0] = f2b(Wsv[((size_t)((l * 64 + kq * 8 + ki) * 2) + k2) * 32 + mm]);
  } else if (idx < T1 + T2 + T3) {
    int r0 = idx - T1 - T2;
    int l = r0 / 6144, r1 = r0 % 6144;
    int k2 = r1 / 3072, r = r1 % 3072;
    int ki = r & 7, tt = r >> 3;
    int mm = tt % 96, kq = tt / 96;
    WvsL[r0] = f2b(Wvs[((size_t)((l * 32 + kq * 8 + ki) * 2) + k2) * 96 + mm]);
  } else if (idx < T1 + T2 + T3 + T4) {
    int r0 = idx - T1 - T2 - T3;
    int l = r0 / 2048, r1 = r0 % 2048;
    int kq = r1 / 512, rem = r1 % 512;
    int n = rem / 8, ki = rem & 7;
    fc1L[r0] = (kq < 2) ? f2b(fc1[l * 1024 + (kq * 8 + ki) * 64 + n]) : (u16)0;
  }
}

__global__ void k_init(const float* __restrict__ x, const float* __restrict__ Wup,
                       float* __restrict__ v, float* __restrict__ v_old,
                       float* __restrict__ xcur, int N) {
  int idx = blockIdx.x * 256 + threadIdx.x;
  if (idx >= N * 32) return;
  int n = idx >> 5, vc = idx & 31;
  float w0 = Wup[vc], w1 = Wup[32 + vc];
#pragma unroll
  for (int c = 0; c < 3; ++c) {
    float val = x[n * 6 + c] * w0 + x[n * 6 + 3 + c] * w1;
    v[idx * 3 + c] = val;
    v_old[idx * 3 + c] = val;
  }
  if (vc < 6) xcur[n * 6 + vc] = x[n * 6 + vc];
}

// ---------------- CSR build ----------------

__global__ void k_zero_i(int* __restrict__ p, int n) {
  int i = blockIdx.x * 256 + threadIdx.x;
  if (i < n) p[i] = 0;
}

__global__ void k_hist(const int* __restrict__ edst, int* __restrict__ deg, int E) {
  int e = blockIdx.x * 256 + threadIdx.x;
  if (e < E) atomicAdd(&deg[edst[e]], 1);
}

__global__ __launch_bounds__(1024) void k_scan(const int* __restrict__ deg,
                                               int* __restrict__ row_ptr,
                                               int* __restrict__ cursor, int N) {
  __shared__ int part[1024];
  int t = threadIdx.x;
  int chunk = (N + 1023) / 1024;
  int base = t * chunk;
  int sum = 0;
  for (int i = 0; i < chunk; ++i) {
    int idx = base + i;
    if (idx < N) sum += deg[idx];
  }
  part[t] = sum;
  __syncthreads();
  for (int off = 1; off < 1024; off <<= 1) {
    int val = (t >= off) ? part[t - off] : 0;
    __syncthreads();
    part[t] += val;
    __syncthreads();
  }
  int run = (t > 0) ? part[t - 1] : 0;
  for (int i = 0; i < chunk; ++i) {
    int idx = base + i;
    if (idx < N) {
      row_ptr[idx] = run;
      cursor[idx] = run;
      run += deg[idx];
    }
  }
  if (t == 1023) row_ptr[N] = part[1023];
}

__global__ void k_scatter(const int* __restrict__ esrc, const int* __restrict__ edst,
                          int* __restrict__ cursor, int* __restrict__ esrc_s,
                          int* __restrict__ edst_s, int E) {
  int e = blockIdx.x * 256 + threadIdx.x;
  if (e < E) {
    int d = edst[e];
    int p = atomicAdd(&cursor[d], 1);
    esrc_s[p] = esrc[e];
    edst_s[p] = d;
  }
}

// ---------------- fused MFMA edge kernel: wave = 32 consecutive CSR-sorted edges ----
// Aggregation fused: per-wave segmented reduction over dst runs, atomicAdd f32 into
// agg[N][192] (cols 0..95 = msg_s[m]; 96 + c*32 + m' = msg_v). No msgbuf round-trip.
template <bool SZERO>
__global__ __launch_bounds__(128) void k_edge_mfma(
    const float* __restrict__ xcur, const float* __restrict__ s, const float* __restrict__ v,
    const int* __restrict__ esrc_s, const int* __restrict__ edst_s,
    const u16* __restrict__ fc1L, const float* __restrict__ b1,
    const u16* __restrict__ fc2L, const u16* __restrict__ WsvL0,
    const u16* __restrict__ WsvL1, const u16* __restrict__ WvsL0,
    const u16* __restrict__ WvsL1, float* __restrict__ aggbuf, int E) {
  __shared__ u16 wbAll[2][32 * WST];
  __shared__ float aAll[2][32][6];
  __shared__ int dAll[2][32];
  int wid = threadIdx.x >> 6, lane = threadIdx.x & 63;
  int e0 = (blockIdx.x * 2 + wid) * 32;
  if (e0 >= E) return;
  u16* wb = wbAll[wid];
  int lrow = lane & 15, lg = lane >> 4;

  // ====== geometry: lane = (el = lane>>1, qq = lane&1); one (edge, vec) per lane ======
  {
    int el = lane >> 1, qq = lane & 1;
    int ge = e0 + el;
    if (ge >= E) ge = E - 1;
    int gs = esrc_s[ge], gd = edst_s[ge];
    const float* ps = xcur + (size_t)gs * 6 + qq * 3;
    const float* pd = xcur + (size_t)gd * 6 + qq * 3;
    float vx = ps[0] - pd[0];
    float vy = ps[1] - pd[1];
    float vz = ps[2] - pd[2];
    float r2 = vx * vx + vy * vy + vz * vz;
    float rr = sqrtf(r2);
    float invr = 1.0f / rr;
    float th = (PI_F / 3.0f) * rr;
    float s1, c1;
    __sincosf(th, &s1, &c1);
    float twc = 2.0f * c1;
    float snm = 0.f, sn = s1;
    float fc = BESSEL_C * invr;
    float f8[8];
#pragma unroll
    for (int nn = 0; nn < 8; ++nn) {
      f8[nn] = fc * sn;
      float nx = twc * sn - snm;
      snm = sn;
      sn = nx;
    }
    float uu = (2.0f / 3.0f) * rr - 2.0f;
    float cut;
    if (uu > 0.f) cut = 0.f;
    else if (uu < -1.f) cut = 1.f;
    else cut = (1.0f - __cosf(PI_F * uu)) * 0.5f;
    float sc = cut * SQRT3 * invr;
    // f region: offset FOFF, 32 rows x 40 u16 (cols 0..15 data, 16..31 zero, 32..39 pad)
    u32* fp = (u32*)(wb + FOFF + el * 40);
#pragma unroll
    for (int i = 0; i < 4; ++i) fp[qq * 4 + i] = pkbf(f8[2 * i], f8[2 * i + 1]);
#pragma unroll
    for (int i = 0; i < 4; ++i) fp[8 + qq * 4 + i] = 0u;
    float* ap = aAll[wid][el];
    ap[qq * 3 + 0] = vx * sc;
    ap[qq * 3 + 1] = vy * sc;
    ap[qq * 3 + 2] = vz * sc;
    if (qq == 0) dAll[wid][el] = gd;
  }
  lds_fence();

  // ====== MLP: hid[32][64] = silu(f @ fc1 + b1) via 8 MFMA (B shared across halves) ====
  {
    bf16x8 fA0 = *(const bf16x8*)(wb + FOFF + lrow * 40 + lg * 8);
    bf16x8 fA1 = *(const bf16x8*)(wb + FOFF + (16 + lrow) * 40 + lg * 8);
    f32x4 hp0[4], hp1[4];
    __builtin_amdgcn_s_setprio(1);
#pragma unroll
    for (int nb = 0; nb < 4; ++nb) {
      bf16x8 bB = *(const bf16x8*)(fc1L + (size_t)(lg * 64 + nb * 16 + lrow) * 8);
      f32x4 z = {0.f, 0.f, 0.f, 0.f};
      hp0[nb] = mfma16(fA0, bB, z);
      hp1[nb] = mfma16(fA1, bB, z);
    }
    __builtin_amdgcn_s_setprio(0);
#pragma unroll
    for (int nb = 0; nb < 4; ++nb) {
      float bias = b1[nb * 16 + lrow];
      int col = nb * 16 + lrow;
      {
        float hv[4];
#pragma unroll
        for (int r = 0; r < 4; ++r) {
          float xv = hp0[nb][r] + bias;
          hv[r] = xv * (1.0f / (1.0f + __expf(-xv)));
        }
        u32 p01 = pkbf(hv[0], hv[1]);
        u32 p23 = pkbf(hv[2], hv[3]);
        wb[(4 * lg + 0) * 72 + col] = (u16)p01;
        wb[(4 * lg + 1) * 72 + col] = (u16)(p01 >> 16);
        wb[(4 * lg + 2) * 72 + col] = (u16)p23;
        wb[(4 * lg + 3) * 72 + col] = (u16)(p23 >> 16);
      }
      {
        float hv[4];
#pragma unroll
        for (int r = 0; r < 4; ++r) {
          float xv = hp1[nb][r] + bias;
          hv[r] = xv * (1.0f / (1.0f + __expf(-xv)));
        }
        u32 p01 = pkbf(hv[0], hv[1]);
        u32 p23 = pkbf(hv[2], hv[3]);
        wb[(16 + 4 * lg + 0) * 72 + col] = (u16)p01;
        wb[(16 + 4 * lg + 1) * 72 + col] = (u16)(p01 >> 16);
        wb[(16 + 4 * lg + 2) * 72 + col] = (u16)p23;
        wb[(16 + 4 * lg + 3) * 72 + col] = (u16)(p23 >> 16);
      }
    }
  }
  lds_fence();

  // hid A-fragments (both halves)
  bf16x8 ha0 = *(const bf16x8*)(wb + lrow * 72 + lg * 8);
  bf16x8 hbf0 = *(const bf16x8*)(wb + lrow * 72 + 32 + lg * 8);
  bf16x8 ha1 = *(const bf16x8*)(wb + (16 + lrow) * 72 + lg * 8);
  bf16x8 hbf1 = *(const bf16x8*)(wb + (16 + lrow) * 72 + 32 + lg * 8);
  lds_fence();   // reads done before wb overwrite

  // ---- GEMM2: w[32,192] = hid @ fc2, B-frags shared across halves; swizzled store
  int xw = lg << 3;
  __builtin_amdgcn_s_setprio(1);
#pragma unroll
  for (int nb = (SZERO ? 8 : 0); nb < 12; ++nb) {
    bf16x8 b0 = *(const bf16x8*)(fc2L + (size_t)(lg * 192 + nb * 16 + lrow) * 8);
    bf16x8 b1v = *(const bf16x8*)(fc2L + (size_t)((4 + lg) * 192 + nb * 16 + lrow) * 8);
    f32x4 z = {0.f, 0.f, 0.f, 0.f};
    f32x4 c0 = mfma16(ha0, b0, z);
    c0 = mfma16(hbf0, b1v, c0);
    f32x4 c1 = mfma16(ha1, b0, z);
    c1 = mfma16(hbf1, b1v, c1);
    int n = nb * 16 + lrow;
    int pn = (n < 128) ? ((n & 1) * 64 + (n >> 1)) : (128 + (n & 1) * 32 + ((n - 128) >> 1));
    int cx = pn ^ xw;
    {
      int rb = (4 * lg) * WST + cx;
      u32 p01 = pkbf(c0[0], c0[1]);
      u32 p23 = pkbf(c0[2], c0[3]);
      wb[rb] = (u16)p01;
      wb[rb + WST] = (u16)(p01 >> 16);
      wb[rb + 2 * WST] = (u16)p23;
      wb[rb + 3 * WST] = (u16)(p23 >> 16);
    }
    {
      int rb = (16 + 4 * lg) * WST + cx;
      u32 p01 = pkbf(c1[0], c1[1]);
      u32 p23 = pkbf(c1[2], c1[3]);
      wb[rb] = (u16)p01;
      wb[rb + WST] = (u16)(p01 >> 16);
      wb[rb + 2 * WST] = (u16)p23;
      wb[rb + 3 * WST] = (u16)(p23 >> 16);
    }
  }
  __builtin_amdgcn_s_setprio(0);
  lds_fence();

  // swizzled row pointers (offsets used below are multiples of 32 -> swizzle-safe)
  const u16* wrow0 = wb + lrow * WST + (((lg ^ (lrow >> 2)) & 3) << 3);
  const u16* wrow1 = wrow0 + 16 * WST;

  int prow0 = e0 + lrow;
  if (prow0 >= E) prow0 = E - 1;
  int prow1 = e0 + 16 + lrow;
  if (prow1 >= E) prow1 = E - 1;
  int srcs[2] = {esrc_s[prow0], esrc_s[prow1]};

  // ---- Q path: T = s_src (.) w1 ; Q = T @ W_sv (B-frags shared across halves)
  f32x4 q0[2][2], q1[2][2];
  if (!SZERO) {
    U8 t0a[2], t0b[2], t1a[2], t1b[2];
#pragma unroll
    for (int h = 0; h < 2; ++h) {
      const u16* wr = h ? wrow1 : wrow0;
      const float* sp = s + (size_t)srcs[h] * 64;
      float sv0[8], sv1[8];
      *(f32x4*)(sv0) = *(const f32x4*)(sp + lg * 8);
      *(f32x4*)(sv0 + 4) = *(const f32x4*)(sp + lg * 8 + 4);
      *(f32x4*)(sv1) = *(const f32x4*)(sp + 32 + lg * 8);
      *(f32x4*)(sv1 + 4) = *(const f32x4*)(sp + 32 + lg * 8 + 4);
      i32x4 W0a = *(const i32x4*)(wr);
      i32x4 W0b = *(const i32x4*)(wr + 32);
      i32x4 W1a = *(const i32x4*)(wr + 64);
      i32x4 W1b = *(const i32x4*)(wr + 96);
#pragma unroll
      for (int j2 = 0; j2 < 4; ++j2) {
        u32 wa = (u32)W0a[j2], wbv = (u32)W0b[j2], wc = (u32)W1a[j2], wd = (u32)W1b[j2];
        t0a[h].w[j2] = pkbf(sv0[2 * j2] * blo(wa), sv0[2 * j2 + 1] * bhi(wa));
        t0b[h].w[j2] = pkbf(sv1[2 * j2] * blo(wbv), sv1[2 * j2 + 1] * bhi(wbv));
        t1a[h].w[j2] = pkbf(sv0[2 * j2] * blo(wc), sv0[2 * j2 + 1] * bhi(wc));
        t1b[h].w[j2] = pkbf(sv1[2 * j2] * blo(wd), sv1[2 * j2 + 1] * bhi(wd));
      }
    }
    __builtin_amdgcn_s_setprio(1);
#pragma unroll
    for (int nb = 0; nb < 2; ++nb) {
      bf16x8 bA = *(const bf16x8*)(WsvL0 + (size_t)(lg * 32 + nb * 16 + lrow) * 8);
      bf16x8 bB = *(const bf16x8*)(WsvL0 + (size_t)((4 + lg) * 32 + nb * 16 + lrow) * 8);
      bf16x8 bC = *(const bf16x8*)(WsvL1 + (size_t)(lg * 32 + nb * 16 + lrow) * 8);
      bf16x8 bD = *(const bf16x8*)(WsvL1 + (size_t)((4 + lg) * 32 + nb * 16 + lrow) * 8);
#pragma unroll
      for (int h = 0; h < 2; ++h) {
        f32x4 z = {0.f, 0.f, 0.f, 0.f};
        f32x4 c = mfma16(t0a[h].v, bA, z);
        c = mfma16(t0b[h].v, bB, c);
        q0[h][nb] = c;
        f32x4 c2 = mfma16(t1a[h].v, bC, z);
        c2 = mfma16(t1b[h].v, bD, c2);
        q1[h][nb] = c2;
      }
    }
    __builtin_amdgcn_s_setprio(0);
  }

  // ---- M path: G = (v_src . a) (.) w2 ; msg_s = G @ Wvs (B-frags shared)
  U8 ga[2], gb[2];
#pragma unroll
  for (int h = 0; h < 2; ++h) {
    const float* ap = aAll[wid][h * 16 + lrow];
    float a00 = ap[0], a01 = ap[1], a02 = ap[2], a10 = ap[3], a11 = ap[4], a12 = ap[5];
    float vl[24];
    const float* vp = v + (size_t)srcs[h] * 96 + lg * 24;
#pragma unroll
    for (int i = 0; i < 6; ++i) *(f32x4*)(vl + 4 * i) = *(const f32x4*)(vp + 4 * i);
    const u16* wr = h ? wrow1 : wrow0;
    i32x4 W2a = *(const i32x4*)(wr + 128);
    i32x4 W2b = *(const i32x4*)(wr + 160);
#pragma unroll
    for (int j2 = 0; j2 < 4; ++j2) {
      float d0a, d1a, d0b, d1b;
      {
        float vx = vl[6 * j2 + 0], vy = vl[6 * j2 + 1], vz = vl[6 * j2 + 2];
        d0a = vx * a00 + vy * a01 + vz * a02;
        d1a = vx * a10 + vy * a11 + vz * a12;
      }
      {
        float vx = vl[6 * j2 + 3], vy = vl[6 * j2 + 4], vz = vl[6 * j2 + 5];
        d0b = vx * a00 + vy * a01 + vz * a02;
        d1b = vx * a10 + vy * a11 + vz * a12;
      }
      u32 wa = (u32)W2a[j2], wbv = (u32)W2b[j2];
      ga[h].w[j2] = pkbf(d0a * blo(wa), d0b * bhi(wa));
      gb[h].w[j2] = pkbf(d1a * blo(wbv), d1b * bhi(wbv));
    }
  }
  f32x4 mS[2][6];
  __builtin_amdgcn_s_setprio(1);
#pragma unroll
  for (int nb = 0; nb < 6; ++nb) {
    bf16x8 b0 = *(const bf16x8*)(WvsL0 + (size_t)(lg * 96 + nb * 16 + lrow) * 8);
    bf16x8 b1v = *(const bf16x8*)(WvsL1 + (size_t)(lg * 96 + nb * 16 + lrow) * 8);
#pragma unroll
    for (int h = 0; h < 2; ++h) {
      f32x4 z = {0.f, 0.f, 0.f, 0.f};
      f32x4 c = mfma16(ga[h].v, b0, z);
      c = mfma16(gb[h].v, b1v, c);
      mS[h][nb] = c;
    }
  }
  __builtin_amdgcn_s_setprio(0);

  // ---- stage final msg rows into wb (overwrite w; swizzled)
  lds_fence();
#pragma unroll
  for (int h = 0; h < 2; ++h) {
    int rbase = (h * 16 + 4 * lg) * WST;
#pragma unroll
    for (int nb = 0; nb < 6; ++nb) {
      u32 p01 = pkbf(mS[h][nb][0], mS[h][nb][1]);
      u32 p23 = pkbf(mS[h][nb][2], mS[h][nb][3]);
      int colx = (nb * 16 + lrow) ^ xw;
      wb[rbase + colx] = (u16)p01;
      wb[rbase + WST + colx] = (u16)(p01 >> 16);
      wb[rbase + 2 * WST + colx] = (u16)p23;
      wb[rbase + 3 * WST + colx] = (u16)(p23 >> 16);
    }
    if (!SZERO) {
#pragma unroll
      for (int nb = 0; nb < 2; ++nb) {
#pragma unroll
        for (int r = 0; r < 4; ++r) {
          int el = h * 16 + 4 * lg + r;
          const float* ap = aAll[wid][el];
          float Q0v = q0[h][nb][r], Q1v = q1[h][nb][r];
          float v0 = Q0v * ap[0] + Q1v * ap[3];
          float v1 = Q0v * ap[1] + Q1v * ap[4];
          float v2 = Q0v * ap[2] + Q1v * ap[5];
          u32 p01 = pkbf(v0, v1);
          int base = el * WST + ((96 + nb * 16 + lrow) ^ xw);
          wb[base] = (u16)p01;
          wb[base + 32] = (u16)(p01 >> 16);
          wb[base + 64] = f2b(v2);
        }
      }
    }
  }
  lds_fence();

  // ---- segmented reduction over dst runs (edges sorted by dst) + atomicAdd ----
  {
    int nrows = E - e0;
    if (nrows > 32) nrows = 32;
    const int* dstv = dAll[wid];
    int c0 = lane, c1 = lane + 64, c2 = lane + 128;
    bool v1ok = SZERO ? (c1 < 96) : true;
    bool v2ok = SZERO ? false : true;
    float acc0 = 0.f, acc1 = 0.f, acc2 = 0.f;
    int prev = dstv[0];
    for (int r = 0; r < nrows; ++r) {
      int d = dstv[r];
      if (d != prev) {   // wave-uniform branch
        float* ab = aggbuf + (size_t)prev * 192;
        atomicAdd(ab + c0, acc0);
        if (v1ok) atomicAdd(ab + c1, acc1);
        if (v2ok) atomicAdd(ab + c2, acc2);
        acc0 = acc1 = acc2 = 0.f;
        prev = d;
      }
      int xo = ((r >> 2) & 3) << 3;
      int rb = r * WST;
      acc0 += b2f(wb[rb + (c0 ^ xo)]);
      if (v1ok) acc1 += b2f(wb[rb + (c1 ^ xo)]);
      if (v2ok) acc2 += b2f(wb[rb + (c2 ^ xo)]);
    }
    float* ab = aggbuf + (size_t)prev * 192;
    atomicAdd(ab + c0, acc0);
    if (v1ok) atomicAdd(ab + c1, acc1);
    if (v2ok) atomicAdd(ab + c2, acc2);
  }
}

// ---------------- node update (2 nodes per 256-thread block; reads dense agg) ------
__global__ __launch_bounds__(256) void k_gnode(
    const float* __restrict__ aggbuf,
    float* __restrict__ s, float* __restrict__ sold, float* __restrict__ v,
    float* __restrict__ vold,
    const float* __restrict__ Amat, const float* __restrict__ Bmat,
    const float* __restrict__ Ws, const float* __restrict__ Wv,
    const float* __restrict__ Wproj, const int* __restrict__ nattr,
    const float* __restrict__ hArr, const float* __restrict__ mixArr, int layer,
    float* __restrict__ xout, int N) {
  int half = threadIdx.x >> 7;
  int t = threadIdx.x & 127;
  int n = blockIdx.x * 2 + half;
  bool active = n < N;
  if (!active) n = N - 1;
  __shared__ float agg[2][192];
  __shared__ float srow[2][64];
  __shared__ float vrow[2][96];
  __shared__ float gateS[2][32];
  __shared__ float vnewS[2][96];
  if (t < 96) {
    agg[half][t] = aggbuf[(size_t)n * 192 + t] * INV_SQRT_NN;
    agg[half][96 + t] = aggbuf[(size_t)n * 192 + 96 + t] * INV_SQRT_NN;
  }
  if (t < 64) srow[half][t] = s[(size_t)n * 64 + t];
  if (t < 96) vrow[half][t] = v[(size_t)n * 96 + t];
  __syncthreads();
  int type = nattr[n];
  float hv = hArr[layer];
  float h2v = hv * hv;
  float mx = mixArr[layer];
  float cs = 0.f;
  if (t < 96) {
    cs = agg[half][t];
    const float* Ac = Amat + (size_t)type * 64 * 96 + t;
#pragma unroll 8
    for (int u = 0; u < 64; ++u) cs += srow[half][u] * Ac[u * 96];
  }
  if (t >= 64 && t < 96) gateS[half][t - 64] = 1.0f / (1.0f + __expf(-cs));
  __syncthreads();
  if (t < 64) {
    float gs = cs * (1.0f / (1.0f + __expf(-cs)));
    float sis = 0.f;
#pragma unroll 8
    for (int u = 0; u < 64; ++u) sis += srow[half][u] * Ws[u * 64 + t];
    float scur = srow[half][t];
    float sprev = sold[(size_t)n * 64 + t];
    float snew = 2.f * scur - sprev + h2v * (mx * gs + (mx - 1.f) * sis);
    if (active) {
      sold[(size_t)n * 64 + t] = scur;
      s[(size_t)n * 64 + t] = snew;
    }
  }
  if (t < 96) {
    int vch = t / 3, c = t - vch * 3;
    float cv = agg[half][96 + c * 32 + vch];
    const float* Bc = Bmat + (size_t)type * 1024 + vch;
    float scv = 0.f, siv = 0.f;
#pragma unroll 8
    for (int u = 0; u < 32; ++u) {
      float vu = vrow[half][u * 3 + c];
      scv += vu * Bc[u * 32];
      siv += vu * Wv[u * 32 + vch];
    }
    cv += scv;
    float gv = cv * gateS[half][vch];
    float vcur = vrow[half][t];
    float vprev = vold[(size_t)n * 96 + t];
    float vnew = 2.f * vcur - vprev + h2v * (mx * gv + (mx - 1.f) * siv);
    if (active) {
      vold[(size_t)n * 96 + t] = vcur;
      v[(size_t)n * 96 + t] = vnew;
    }
    vnewS[half][t] = vnew;
  }
  __syncthreads();
  if (t < 6 && active) {
    int i = t / 3, c = t - i * 3;
    float acc = 0.f;
#pragma unroll
    for (int vo = 0; vo < 32; ++vo) acc += vnewS[half][vo * 3 + c] * Wproj[vo * 2 + i];
    xout[(size_t)n * 6 + t] = acc;
  }
}

extern "C" void kernel_launch(void* const* d_in, const int* in_sizes, int n_in,
                              void* d_out, int out_size, void* d_ws, size_t ws_size,
                              hipStream_t stream) {
  const float* x = (const float*)d_in[0];
  const float* emb = (const float*)d_in[1];
  const float* Wup = (const float*)d_in[2];
  const float* Wproj = (const float*)d_in[3];
  const float* fc1 = (const float*)d_in[4];
  const float* b1 = (const float*)d_in[5];
  const float* fc2 = (const float*)d_in[6];
  const float* Wsv = (const float*)d_in[7];
  const float* Wvs = (const float*)d_in[8];
  const float* Wscs = (const float*)d_in[9];
  const float* Wscv = (const float*)d_in[10];
  const float* Ws = (const float*)d_in[11];
  const float* Wv = (const float*)d_in[12];
  const float* hArr = (const float*)d_in[13];
  const float* mixArr = (const float*)d_in[14];
  const int* nattr = (const int*)d_in[15];
  const int* esrc = (const int*)d_in[16];
  const int* edst = (const int*)d_in[17];

  const int N = in_sizes[0] / 6;
  const int E = in_sizes[16];

  float* ws = (float*)d_ws;
  size_t off = 0;
  auto alloc = [&](size_t nf) {
    float* p = ws + off;
    off += (nf + 3) & ~(size_t)3;
    return p;
  };
  float* sbuf = alloc((size_t)N * 64);
  float* sold = alloc((size_t)N * 64);
  float* vbuf = alloc((size_t)N * 96);
  float* vold = alloc((size_t)N * 96);
  float* xcur = alloc((size_t)N * 6);
  float* aggbuf = alloc((size_t)N * 192);
  float* Amat = alloc((size_t)cL * cNT * 64 * 96);
  float* Bmat = alloc((size_t)cL * cNT * 32 * 32);
  u16* fc2L = (u16*)alloc((size_t)cL * 6144);       // L*12288 bf16
  u16* WsvL = (u16*)alloc((size_t)cL * 2048);       // L*2*2048 bf16
  u16* WvsL = (u16*)alloc((size_t)cL * 3072);       // L*2*3072 bf16
  u16* fc1L = (u16*)alloc((size_t)cL * 1024);       // L*2048 bf16 (kq padded to 4)
  int* deg = (int*)alloc((size_t)(N + 4));
  int* row_ptr = (int*)alloc((size_t)(N + 4));
  int* cursor = (int*)alloc((size_t)(N + 4));
  int* esrc_s = (int*)alloc((size_t)E);
  int* edst_s = (int*)alloc((size_t)E);

  // init
  hipMemsetAsync(sbuf, 0, sizeof(float) * (size_t)N * 128, stream);  // sbuf + sold
  k_init<<<(N * 32 + 255) / 256, 256, 0, stream>>>(x, Wup, vbuf, vold, xcur, N);
  k_precompA<<<(cL * cNT * 64 * 96 + 255) / 256, 256, 0, stream>>>(emb, Wscs, Amat);
  k_precompB<<<(cL * cNT * 32 * 32 + 255) / 256, 256, 0, stream>>>(emb, Wscv, Bmat);
  {
    int tot = cL * 12288 + cL * 4096 + cL * 6144 + cL * 2048;
    k_packB<<<(tot + 255) / 256, 256, 0, stream>>>(fc2, Wsv, Wvs, fc1, fc2L, WsvL, WvsL, fc1L);
  }
  k_zero_i<<<(N + 255) / 256, 256, 0, stream>>>(deg, N);
  k_hist<<<(E + 255) / 256, 256, 0, stream>>>(edst, deg, E);
  k_scan<<<1, 1024, 0, stream>>>(deg, row_ptr, cursor, N);
  k_scatter<<<(E + 255) / 256, 256, 0, stream>>>(esrc, edst, cursor, esrc_s, edst_s, E);

  int eblocks = (E + 63) / 64;
  int gblocks = (N + 1) / 2;
  for (int l = 0; l < cL; ++l) {
    hipMemsetAsync(aggbuf, 0, sizeof(float) * (size_t)N * 192, stream);
    if (l == 0)
      k_edge_mfma<true><<<eblocks, 128, 0, stream>>>(
          xcur, sbuf, vbuf, esrc_s, edst_s, fc1L + l * 2048, b1 + l * 64,
          fc2L + l * 12288, WsvL + l * 4096, WsvL + l * 4096 + 2048,
          WvsL + l * 6144, WvsL + l * 6144 + 3072, aggbuf, E);
    else
      k_edge_mfma<false><<<eblocks, 128, 0, stream>>>(
          xcur, sbuf, vbuf, esrc_s, edst_s, fc1L + l * 2048, b1 + l * 64,
          fc2L + l * 12288, WsvL + l * 4096, WsvL + l * 4096 + 2048,
          WvsL + l * 6144, WvsL + l * 6144 + 3072, aggbuf, E);
    float* xout = (l == cL - 1) ? (float*)d_out : xcur;
    k_gnode<<<gblocks, 256, 0, stream>>>(
        aggbuf, sbuf, sold, vbuf, vold, Amat + (size_t)l * cNT * 64 * 96,
        Bmat + (size_t)l * cNT * 1024, Ws + l * 4096, Wv + l * 1024, Wproj, nattr,
        hArr, mixArr, l, xout, N);
  }
}

// Round 15
// 503.681 us; speedup vs baseline: 1.1004x; 1.1004x over previous
//
#include <hip/hip_runtime.h>
#include <math.h>

constexpr int cNS = 64, cNV = 32, cNB = 8, cL = 4, cEMB = 32, cNT = 10;
constexpr float PI_F = 3.14159265358979323846f;
constexpr float INV_SQRT_NN = 0.17677669529663687f;   // 1/sqrt(32)
constexpr float BESSEL_C = 2.3094010767585034f;       // sqrt(2/3)*sqrt(8)
constexpr float SQRT3 = 1.7320508075688772f;

typedef unsigned short u16;
typedef unsigned int u32;
typedef unsigned long long u64;
typedef __attribute__((ext_vector_type(8))) short bf16x8;
typedef __attribute__((ext_vector_type(4))) float f32x4;
typedef __attribute__((ext_vector_type(2))) float f32x2;
typedef __attribute__((ext_vector_type(4))) int i32x4;

__device__ __forceinline__ u16 f2b(float x) {   // f32 -> bf16 RNE (scalar fallback)
  u32 u = __float_as_uint(x);
  return (u16)((u + 0x7fffu + ((u >> 16) & 1u)) >> 16);
}
__device__ __forceinline__ float b2f(u16 h) { return __uint_as_float(((u32)h) << 16); }
__device__ __forceinline__ float blo(u32 w) { return __uint_as_float(w << 16); }
__device__ __forceinline__ float bhi(u32 w) { return __uint_as_float(w & 0xffff0000u); }

// HW packed f32->bf16 (2 values, 1 instruction)
__device__ __forceinline__ u32 pkbf(float lo, float hi) {
  u32 r;
  asm("v_cvt_pk_bf16_f32 %0, %1, %2" : "=v"(r) : "v"(lo), "v"(hi));
  return r;
}

// lgkmcnt(0) + hard scheduling fence (rule #18)
__device__ __forceinline__ void lds_fence() {
  asm volatile("s_waitcnt lgkmcnt(0)" ::: "memory");
  __builtin_amdgcn_sched_barrier(0);
}

union U8 { bf16x8 v; u32 w[4]; };

__device__ __forceinline__ f32x4 mfma16(bf16x8 a, bf16x8 b, f32x4 c) {
  return __builtin_amdgcn_mfma_f32_16x16x32_bf16(a, b, c, 0, 0, 0);
}

// ---------------- precompute kernels ----------------

__global__ void k_precompA(const float* __restrict__ emb, const float* __restrict__ Wss,
                           float* __restrict__ A) {
  int idx = blockIdx.x * 256 + threadIdx.x;
  if (idx >= cL * cNT * 64 * 96) return;
  int m = idx % 96;
  int u = (idx / 96) % 64;
  int t = (idx / (96 * 64)) % cNT;
  int l = idx / (96 * 64 * cNT);
  float acc = 0.f;
#pragma unroll
  for (int e = 0; e < 32; ++e)
    acc += emb[t * 32 + e] * Wss[((size_t)(l * 64 + u) * 32 + e) * 96 + m];
  A[idx] = acc;
}

__global__ void k_precompB(const float* __restrict__ emb, const float* __restrict__ Wsv_,
                           float* __restrict__ B) {
  int idx = blockIdx.x * 256 + threadIdx.x;
  if (idx >= cL * cNT * 32 * 32) return;
  int vo = idx % 32;
  int u = (idx / 32) % 32;
  int t = (idx / 1024) % cNT;
  int l = idx / (1024 * cNT);
  float acc = 0.f;
#pragma unroll
  for (int e = 0; e < 32; ++e)
    acc += emb[t * 32 + e] * Wsv_[((size_t)(l * 32 + u) * 32 + e) * 32 + vo];
  B[idx] = acc;
}

// pack fc2 / W_sv / W_vs / fc1 into bf16 MFMA-B layouts: BL[(k/8)*N*8 + n*8 + (k%8)]
__global__ void k_packB(const float* __restrict__ fc2, const float* __restrict__ Wsv,
                        const float* __restrict__ Wvs, const float* __restrict__ fc1,
                        u16* __restrict__ fc2L, u16* __restrict__ WsvL,
                        u16* __restrict__ WvsL, u16* __restrict__ fc1L) {
  int idx = blockIdx.x * 256 + threadIdx.x;
  const int T1 = cL * 12288, T2 = cL * 2 * 2048, T3 = cL * 2 * 3072, T4 = cL * 2048;
  if (idx < T1) {
    int l = idx / 12288, r = idx % 12288;
    int ki = r & 7, tt = r >> 3;
    int nn = tt % 192, kq = tt / 192;
    fc2L[idx] = f2b(fc2[((size_t)(l * 64) + kq * 8 + ki) * 192 + nn]);
  } else if (idx < T1 + T2) {
    int r0 = idx - T1;
    int l = r0 / 4096, r1 = r0 % 4096;
    int k2 = r1 / 2048, r = r1 % 2048;
    int ki = r & 7, tt = r >> 3;
    int mm = tt % 32, kq = tt / 32;
    WsvL[r0] = f2b(Wsv[((size_t)((l * 64 + kq * 8 + ki) * 2) + k2) * 32 + mm]);
  } else if (idx < T1 + T2 + T3) {
    int r0 = idx - T1 - T2;
    int l = r0 / 6144, r1 = r0 % 6144;
    int k2 = r1 / 3072, r = r1 % 3072;
    int ki = r & 7, tt = r >> 3;
    int mm = tt % 96, kq = tt / 96;
    WvsL[r0] = f2b(Wvs[((size_t)((l * 32 + kq * 8 + ki) * 2) + k2) * 96 + mm]);
  } else if (idx < T1 + T2 + T3 + T4) {
    int r0 = idx - T1 - T2 - T3;
    int l = r0 / 2048, r1 = r0 % 2048;
    int kq = r1 / 512, rem = r1 % 512;
    int n = rem / 8, ki = rem & 7;
    fc1L[r0] = (kq < 2) ? f2b(fc1[l * 1024 + (kq * 8 + ki) * 64 + n]) : (u16)0;
  }
}

__global__ void k_init(const float* __restrict__ x, const float* __restrict__ Wup,
                       float* __restrict__ v, float* __restrict__ v_old,
                       float* __restrict__ xcur, int N) {
  int idx = blockIdx.x * 256 + threadIdx.x;
  if (idx >= N * 32) return;
  int n = idx >> 5, vc = idx & 31;
  float w0 = Wup[vc], w1 = Wup[32 + vc];
#pragma unroll
  for (int c = 0; c < 3; ++c) {
    float val = x[n * 6 + c] * w0 + x[n * 6 + 3 + c] * w1;
    v[idx * 3 + c] = val;
    v_old[idx * 3 + c] = val;
  }
  if (vc < 6) xcur[n * 6 + vc] = x[n * 6 + vc];
}

// ---------------- CSR build ----------------

__global__ void k_zero_i(int* __restrict__ p, int n) {
  int i = blockIdx.x * 256 + threadIdx.x;
  if (i < n) p[i] = 0;
}

__global__ void k_hist(const int* __restrict__ edst, int* __restrict__ deg, int E) {
  int e = blockIdx.x * 256 + threadIdx.x;
  if (e < E) atomicAdd(&deg[edst[e]], 1);
}

__global__ __launch_bounds__(1024) void k_scan(const int* __restrict__ deg,
                                               int* __restrict__ row_ptr,
                                               int* __restrict__ cursor, int N) {
  __shared__ int part[1024];
  int t = threadIdx.x;
  int chunk = (N + 1023) / 1024;
  int base = t * chunk;
  int sum = 0;
  for (int i = 0; i < chunk; ++i) {
    int idx = base + i;
    if (idx < N) sum += deg[idx];
  }
  part[t] = sum;
  __syncthreads();
  for (int off = 1; off < 1024; off <<= 1) {
    int val = (t >= off) ? part[t - off] : 0;
    __syncthreads();
    part[t] += val;
    __syncthreads();
  }
  int run = (t > 0) ? part[t - 1] : 0;
  for (int i = 0; i < chunk; ++i) {
    int idx = base + i;
    if (idx < N) {
      row_ptr[idx] = run;
      cursor[idx] = run;
      run += deg[idx];
    }
  }
  if (t == 1023) row_ptr[N] = part[1023];
}

__global__ void k_scatter(const int* __restrict__ esrc, const int* __restrict__ edst,
                          int* __restrict__ cursor, int* __restrict__ esrc_s,
                          int* __restrict__ edst_s, int E) {
  int e = blockIdx.x * 256 + threadIdx.x;
  if (e < E) {
    int d = edst[e];
    int p = atomicAdd(&cursor[d], 1);
    esrc_s[p] = esrc[e];
    edst_s[p] = d;
  }
}

// ---------------- fused MFMA edge kernel: wave = 32 consecutive CSR-sorted edges ----
// Aggregation fused: per-wave segmented reduction over dst runs, atomicAdd f32 into
// agg[N][192] (cols 0..95 = msg_s[m]; 96 + c*32 + m' = msg_v). No msgbuf round-trip.
// Round-13 configuration (WST=200, no setprio) — round 14's WST=196+setprio regressed
// (VGPR 84->104, achieved occupancy fell); do not reintroduce without A/B.
template <bool SZERO>
__global__ __launch_bounds__(128) void k_edge_mfma(
    const float* __restrict__ xcur, const float* __restrict__ s, const float* __restrict__ v,
    const int* __restrict__ esrc_s, const int* __restrict__ edst_s,
    const u16* __restrict__ fc1L, const float* __restrict__ b1,
    const u16* __restrict__ fc2L, const u16* __restrict__ WsvL0,
    const u16* __restrict__ WsvL1, const u16* __restrict__ WvsL0,
    const u16* __restrict__ WvsL1, float* __restrict__ aggbuf, int E) {
  __shared__ u16 wbAll[2][32 * 200];
  __shared__ float aAll[2][32][6];
  __shared__ int dAll[2][32];
  int wid = threadIdx.x >> 6, lane = threadIdx.x & 63;
  int e0 = (blockIdx.x * 2 + wid) * 32;
  if (e0 >= E) return;
  u16* wb = wbAll[wid];
  int lrow = lane & 15, lg = lane >> 4;

  // ====== geometry: lane = (el = lane>>1, qq = lane&1); one (edge, vec) per lane ======
  {
    int el = lane >> 1, qq = lane & 1;
    int ge = e0 + el;
    if (ge >= E) ge = E - 1;
    int gs = esrc_s[ge], gd = edst_s[ge];
    const float* ps = xcur + (size_t)gs * 6 + qq * 3;
    const float* pd = xcur + (size_t)gd * 6 + qq * 3;
    float vx = ps[0] - pd[0];
    float vy = ps[1] - pd[1];
    float vz = ps[2] - pd[2];
    float r2 = vx * vx + vy * vy + vz * vz;
    float rr = sqrtf(r2);
    float invr = 1.0f / rr;
    float th = (PI_F / 3.0f) * rr;
    float s1, c1;
    __sincosf(th, &s1, &c1);
    float twc = 2.0f * c1;
    float snm = 0.f, sn = s1;
    float fc = BESSEL_C * invr;
    float f8[8];
#pragma unroll
    for (int nn = 0; nn < 8; ++nn) {
      f8[nn] = fc * sn;
      float nx = twc * sn - snm;
      snm = sn;
      sn = nx;
    }
    float uu = (2.0f / 3.0f) * rr - 2.0f;
    float cut;
    if (uu > 0.f) cut = 0.f;
    else if (uu < -1.f) cut = 1.f;
    else cut = (1.0f - __cosf(PI_F * uu)) * 0.5f;
    float sc = cut * SQRT3 * invr;
    // f region: offset 5120, 32 rows x 40 u16 (cols 0..15 data, 16..31 zero, 32..39 pad)
    u32* fp = (u32*)(wb + 5120 + el * 40);
#pragma unroll
    for (int i = 0; i < 4; ++i) fp[qq * 4 + i] = pkbf(f8[2 * i], f8[2 * i + 1]);
#pragma unroll
    for (int i = 0; i < 4; ++i) fp[8 + qq * 4 + i] = 0u;
    float* ap = aAll[wid][el];
    ap[qq * 3 + 0] = vx * sc;
    ap[qq * 3 + 1] = vy * sc;
    ap[qq * 3 + 2] = vz * sc;
    if (qq == 0) dAll[wid][el] = gd;
  }
  lds_fence();

  // ====== MLP: hid[32][64] = silu(f @ fc1 + b1) via 8 MFMA (B shared across halves) ====
  {
    bf16x8 fA0 = *(const bf16x8*)(wb + 5120 + lrow * 40 + lg * 8);
    bf16x8 fA1 = *(const bf16x8*)(wb + 5120 + (16 + lrow) * 40 + lg * 8);
    f32x4 hp0[4], hp1[4];
#pragma unroll
    for (int nb = 0; nb < 4; ++nb) {
      bf16x8 bB = *(const bf16x8*)(fc1L + (size_t)(lg * 64 + nb * 16 + lrow) * 8);
      f32x4 z = {0.f, 0.f, 0.f, 0.f};
      hp0[nb] = mfma16(fA0, bB, z);
      hp1[nb] = mfma16(fA1, bB, z);
    }
#pragma unroll
    for (int nb = 0; nb < 4; ++nb) {
      float bias = b1[nb * 16 + lrow];
      int col = nb * 16 + lrow;
      {
        float hv[4];
#pragma unroll
        for (int r = 0; r < 4; ++r) {
          float xv = hp0[nb][r] + bias;
          hv[r] = xv * (1.0f / (1.0f + __expf(-xv)));
        }
        u32 p01 = pkbf(hv[0], hv[1]);
        u32 p23 = pkbf(hv[2], hv[3]);
        wb[(4 * lg + 0) * 72 + col] = (u16)p01;
        wb[(4 * lg + 1) * 72 + col] = (u16)(p01 >> 16);
        wb[(4 * lg + 2) * 72 + col] = (u16)p23;
        wb[(4 * lg + 3) * 72 + col] = (u16)(p23 >> 16);
      }
      {
        float hv[4];
#pragma unroll
        for (int r = 0; r < 4; ++r) {
          float xv = hp1[nb][r] + bias;
          hv[r] = xv * (1.0f / (1.0f + __expf(-xv)));
        }
        u32 p01 = pkbf(hv[0], hv[1]);
        u32 p23 = pkbf(hv[2], hv[3]);
        wb[(16 + 4 * lg + 0) * 72 + col] = (u16)p01;
        wb[(16 + 4 * lg + 1) * 72 + col] = (u16)(p01 >> 16);
        wb[(16 + 4 * lg + 2) * 72 + col] = (u16)p23;
        wb[(16 + 4 * lg + 3) * 72 + col] = (u16)(p23 >> 16);
      }
    }
  }
  lds_fence();

  // hid A-fragments (both halves)
  bf16x8 ha0 = *(const bf16x8*)(wb + lrow * 72 + lg * 8);
  bf16x8 hbf0 = *(const bf16x8*)(wb + lrow * 72 + 32 + lg * 8);
  bf16x8 ha1 = *(const bf16x8*)(wb + (16 + lrow) * 72 + lg * 8);
  bf16x8 hbf1 = *(const bf16x8*)(wb + (16 + lrow) * 72 + 32 + lg * 8);
  lds_fence();   // reads done before wb overwrite

  // ---- GEMM2: w[32,192] = hid @ fc2, B-frags shared across halves; swizzled store
  int xw = lg << 3;
#pragma unroll
  for (int nb = (SZERO ? 8 : 0); nb < 12; ++nb) {
    bf16x8 b0 = *(const bf16x8*)(fc2L + (size_t)(lg * 192 + nb * 16 + lrow) * 8);
    bf16x8 b1v = *(const bf16x8*)(fc2L + (size_t)((4 + lg) * 192 + nb * 16 + lrow) * 8);
    f32x4 z = {0.f, 0.f, 0.f, 0.f};
    f32x4 c0 = mfma16(ha0, b0, z);
    c0 = mfma16(hbf0, b1v, c0);
    f32x4 c1 = mfma16(ha1, b0, z);
    c1 = mfma16(hbf1, b1v, c1);
    int n = nb * 16 + lrow;
    int pn = (n < 128) ? ((n & 1) * 64 + (n >> 1)) : (128 + (n & 1) * 32 + ((n - 128) >> 1));
    int cx = pn ^ xw;
    {
      int rb = (4 * lg) * 200 + cx;
      u32 p01 = pkbf(c0[0], c0[1]);
      u32 p23 = pkbf(c0[2], c0[3]);
      wb[rb] = (u16)p01;
      wb[rb + 200] = (u16)(p01 >> 16);
      wb[rb + 400] = (u16)p23;
      wb[rb + 600] = (u16)(p23 >> 16);
    }
    {
      int rb = (16 + 4 * lg) * 200 + cx;
      u32 p01 = pkbf(c1[0], c1[1]);
      u32 p23 = pkbf(c1[2], c1[3]);
      wb[rb] = (u16)p01;
      wb[rb + 200] = (u16)(p01 >> 16);
      wb[rb + 400] = (u16)p23;
      wb[rb + 600] = (u16)(p23 >> 16);
    }
  }
  lds_fence();

  // swizzled row pointers (offsets used below are multiples of 32 -> swizzle-safe)
  const u16* wrow0 = wb + lrow * 200 + (((lg ^ (lrow >> 2)) & 3) << 3);
  const u16* wrow1 = wrow0 + 3200;

  int prow0 = e0 + lrow;
  if (prow0 >= E) prow0 = E - 1;
  int prow1 = e0 + 16 + lrow;
  if (prow1 >= E) prow1 = E - 1;
  int srcs[2] = {esrc_s[prow0], esrc_s[prow1]};

  // ---- Q path: T = s_src (.) w1 ; Q = T @ W_sv (B-frags shared across halves)
  f32x4 q0[2][2], q1[2][2];
  if (!SZERO) {
    U8 t0a[2], t0b[2], t1a[2], t1b[2];
#pragma unroll
    for (int h = 0; h < 2; ++h) {
      const u16* wr = h ? wrow1 : wrow0;
      const float* sp = s + (size_t)srcs[h] * 64;
      float sv0[8], sv1[8];
      *(f32x4*)(sv0) = *(const f32x4*)(sp + lg * 8);
      *(f32x4*)(sv0 + 4) = *(const f32x4*)(sp + lg * 8 + 4);
      *(f32x4*)(sv1) = *(const f32x4*)(sp + 32 + lg * 8);
      *(f32x4*)(sv1 + 4) = *(const f32x4*)(sp + 32 + lg * 8 + 4);
      i32x4 W0a = *(const i32x4*)(wr);
      i32x4 W0b = *(const i32x4*)(wr + 32);
      i32x4 W1a = *(const i32x4*)(wr + 64);
      i32x4 W1b = *(const i32x4*)(wr + 96);
#pragma unroll
      for (int j2 = 0; j2 < 4; ++j2) {
        u32 wa = (u32)W0a[j2], wbv = (u32)W0b[j2], wc = (u32)W1a[j2], wd = (u32)W1b[j2];
        t0a[h].w[j2] = pkbf(sv0[2 * j2] * blo(wa), sv0[2 * j2 + 1] * bhi(wa));
        t0b[h].w[j2] = pkbf(sv1[2 * j2] * blo(wbv), sv1[2 * j2 + 1] * bhi(wbv));
        t1a[h].w[j2] = pkbf(sv0[2 * j2] * blo(wc), sv0[2 * j2 + 1] * bhi(wc));
        t1b[h].w[j2] = pkbf(sv1[2 * j2] * blo(wd), sv1[2 * j2 + 1] * bhi(wd));
      }
    }
#pragma unroll
    for (int nb = 0; nb < 2; ++nb) {
      bf16x8 bA = *(const bf16x8*)(WsvL0 + (size_t)(lg * 32 + nb * 16 + lrow) * 8);
      bf16x8 bB = *(const bf16x8*)(WsvL0 + (size_t)((4 + lg) * 32 + nb * 16 + lrow) * 8);
      bf16x8 bC = *(const bf16x8*)(WsvL1 + (size_t)(lg * 32 + nb * 16 + lrow) * 8);
      bf16x8 bD = *(const bf16x8*)(WsvL1 + (size_t)((4 + lg) * 32 + nb * 16 + lrow) * 8);
#pragma unroll
      for (int h = 0; h < 2; ++h) {
        f32x4 z = {0.f, 0.f, 0.f, 0.f};
        f32x4 c = mfma16(t0a[h].v, bA, z);
        c = mfma16(t0b[h].v, bB, c);
        q0[h][nb] = c;
        f32x4 c2 = mfma16(t1a[h].v, bC, z);
        c2 = mfma16(t1b[h].v, bD, c2);
        q1[h][nb] = c2;
      }
    }
  }

  // ---- M path: G = (v_src . a) (.) w2 ; msg_s = G @ Wvs (B-frags shared)
  U8 ga[2], gb[2];
#pragma unroll
  for (int h = 0; h < 2; ++h) {
    const float* ap = aAll[wid][h * 16 + lrow];
    float a00 = ap[0], a01 = ap[1], a02 = ap[2], a10 = ap[3], a11 = ap[4], a12 = ap[5];
    float vl[24];
    const float* vp = v + (size_t)srcs[h] * 96 + lg * 24;
#pragma unroll
    for (int i = 0; i < 6; ++i) *(f32x4*)(vl + 4 * i) = *(const f32x4*)(vp + 4 * i);
    const u16* wr = h ? wrow1 : wrow0;
    i32x4 W2a = *(const i32x4*)(wr + 128);
    i32x4 W2b = *(const i32x4*)(wr + 160);
#pragma unroll
    for (int j2 = 0; j2 < 4; ++j2) {
      float d0a, d1a, d0b, d1b;
      {
        float vx = vl[6 * j2 + 0], vy = vl[6 * j2 + 1], vz = vl[6 * j2 + 2];
        d0a = vx * a00 + vy * a01 + vz * a02;
        d1a = vx * a10 + vy * a11 + vz * a12;
      }
      {
        float vx = vl[6 * j2 + 3], vy = vl[6 * j2 + 4], vz = vl[6 * j2 + 5];
        d0b = vx * a00 + vy * a01 + vz * a02;
        d1b = vx * a10 + vy * a11 + vz * a12;
      }
      u32 wa = (u32)W2a[j2], wbv = (u32)W2b[j2];
      ga[h].w[j2] = pkbf(d0a * blo(wa), d0b * bhi(wa));
      gb[h].w[j2] = pkbf(d1a * blo(wbv), d1b * bhi(wbv));
    }
  }
  f32x4 mS[2][6];
#pragma unroll
  for (int nb = 0; nb < 6; ++nb) {
    bf16x8 b0 = *(const bf16x8*)(WvsL0 + (size_t)(lg * 96 + nb * 16 + lrow) * 8);
    bf16x8 b1v = *(const bf16x8*)(WvsL1 + (size_t)(lg * 96 + nb * 16 + lrow) * 8);
#pragma unroll
    for (int h = 0; h < 2; ++h) {
      f32x4 z = {0.f, 0.f, 0.f, 0.f};
      f32x4 c = mfma16(ga[h].v, b0, z);
      c = mfma16(gb[h].v, b1v, c);
      mS[h][nb] = c;
    }
  }

  // ---- stage final msg rows into wb (overwrite w; swizzled)
  lds_fence();
#pragma unroll
  for (int h = 0; h < 2; ++h) {
    int rbase = (h * 16 + 4 * lg) * 200;
#pragma unroll
    for (int nb = 0; nb < 6; ++nb) {
      u32 p01 = pkbf(mS[h][nb][0], mS[h][nb][1]);
      u32 p23 = pkbf(mS[h][nb][2], mS[h][nb][3]);
      int colx = (nb * 16 + lrow) ^ xw;
      wb[rbase + colx] = (u16)p01;
      wb[rbase + 200 + colx] = (u16)(p01 >> 16);
      wb[rbase + 400 + colx] = (u16)p23;
      wb[rbase + 600 + colx] = (u16)(p23 >> 16);
    }
    if (!SZERO) {
#pragma unroll
      for (int nb = 0; nb < 2; ++nb) {
#pragma unroll
        for (int r = 0; r < 4; ++r) {
          int el = h * 16 + 4 * lg + r;
          const float* ap = aAll[wid][el];
          float Q0v = q0[h][nb][r], Q1v = q1[h][nb][r];
          float v0 = Q0v * ap[0] + Q1v * ap[3];
          float v1 = Q0v * ap[1] + Q1v * ap[4];
          float v2 = Q0v * ap[2] + Q1v * ap[5];
          u32 p01 = pkbf(v0, v1);
          int base = el * 200 + ((96 + nb * 16 + lrow) ^ xw);
          wb[base] = (u16)p01;
          wb[base + 32] = (u16)(p01 >> 16);
          wb[base + 64] = f2b(v2);
        }
      }
    }
  }
  lds_fence();

  // ---- segmented reduction over dst runs (edges sorted by dst) + atomicAdd ----
  {
    int nrows = E - e0;
    if (nrows > 32) nrows = 32;
    const int* dstv = dAll[wid];
    int c0 = lane, c1 = lane + 64, c2 = lane + 128;
    bool v1ok = SZERO ? (c1 < 96) : true;
    bool v2ok = SZERO ? false : true;
    float acc0 = 0.f, acc1 = 0.f, acc2 = 0.f;
    int prev = dstv[0];
    for (int r = 0; r < nrows; ++r) {
      int d = dstv[r];
      if (d != prev) {   // wave-uniform branch
        float* ab = aggbuf + (size_t)prev * 192;
        atomicAdd(ab + c0, acc0);
        if (v1ok) atomicAdd(ab + c1, acc1);
        if (v2ok) atomicAdd(ab + c2, acc2);
        acc0 = acc1 = acc2 = 0.f;
        prev = d;
      }
      int xo = ((r >> 2) & 3) << 3;
      int rb = r * 200;
      acc0 += b2f(wb[rb + (c0 ^ xo)]);
      if (v1ok) acc1 += b2f(wb[rb + (c1 ^ xo)]);
      if (v2ok) acc2 += b2f(wb[rb + (c2 ^ xo)]);
    }
    float* ab = aggbuf + (size_t)prev * 192;
    atomicAdd(ab + c0, acc0);
    if (v1ok) atomicAdd(ab + c1, acc1);
    if (v2ok) atomicAdd(ab + c2, acc2);
  }
}

// ---------------- node update (2 nodes per 256-thread block; reads dense agg) ------
// ZERO_AGG: after reading agg, write zeros back so the next layer needs no memset.
template <bool ZERO_AGG>
__global__ __launch_bounds__(256) void k_gnode(
    float* __restrict__ aggbuf,
    float* __restrict__ s, float* __restrict__ sold, float* __restrict__ v,
    float* __restrict__ vold,
    const float* __restrict__ Amat, const float* __restrict__ Bmat,
    const float* __restrict__ Ws, const float* __restrict__ Wv,
    const float* __restrict__ Wproj, const int* __restrict__ nattr,
    const float* __restrict__ hArr, const float* __restrict__ mixArr, int layer,
    float* __restrict__ xout, int N) {
  int half = threadIdx.x >> 7;
  int t = threadIdx.x & 127;
  int n = blockIdx.x * 2 + half;
  bool active = n < N;
  if (!active) n = N - 1;
  __shared__ float agg[2][192];
  __shared__ float srow[2][64];
  __shared__ float vrow[2][96];
  __shared__ float gateS[2][32];
  __shared__ float vnewS[2][96];
  if (t < 96) {
    agg[half][t] = aggbuf[(size_t)n * 192 + t] * INV_SQRT_NN;
    agg[half][96 + t] = aggbuf[(size_t)n * 192 + 96 + t] * INV_SQRT_NN;
    if (ZERO_AGG && active) {
      aggbuf[(size_t)n * 192 + t] = 0.f;
      aggbuf[(size_t)n * 192 + 96 + t] = 0.f;
    }
  }
  if (t < 64) srow[half][t] = s[(size_t)n * 64 + t];
  if (t < 96) vrow[half][t] = v[(size_t)n * 96 + t];
  __syncthreads();
  int type = nattr[n];
  float hv = hArr[layer];
  float h2v = hv * hv;
  float mx = mixArr[layer];
  float cs = 0.f;
  if (t < 96) {
    cs = agg[half][t];
    const float* Ac = Amat + (size_t)type * 64 * 96 + t;
#pragma unroll 8
    for (int u = 0; u < 64; ++u) cs += srow[half][u] * Ac[u * 96];
  }
  if (t >= 64 && t < 96) gateS[half][t - 64] = 1.0f / (1.0f + __expf(-cs));
  __syncthreads();
  if (t < 64) {
    float gs = cs * (1.0f / (1.0f + __expf(-cs)));
    float sis = 0.f;
#pragma unroll 8
    for (int u = 0; u < 64; ++u) sis += srow[half][u] * Ws[u * 64 + t];
    float scur = srow[half][t];
    float sprev = sold[(size_t)n * 64 + t];
    float snew = 2.f * scur - sprev + h2v * (mx * gs + (mx - 1.f) * sis);
    if (active) {
      sold[(size_t)n * 64 + t] = scur;
      s[(size_t)n * 64 + t] = snew;
    }
  }
  if (t < 96) {
    int vch = t / 3, c = t - vch * 3;
    float cv = agg[half][96 + c * 32 + vch];
    const float* Bc = Bmat + (size_t)type * 1024 + vch;
    float scv = 0.f, siv = 0.f;
#pragma unroll 8
    for (int u = 0; u < 32; ++u) {
      float vu = vrow[half][u * 3 + c];
      scv += vu * Bc[u * 32];
      siv += vu * Wv[u * 32 + vch];
    }
    cv += scv;
    float gv = cv * gateS[half][vch];
    float vcur = vrow[half][t];
    float vprev = vold[(size_t)n * 96 + t];
    float vnew = 2.f * vcur - vprev + h2v * (mx * gv + (mx - 1.f) * siv);
    if (active) {
      vold[(size_t)n * 96 + t] = vcur;
      v[(size_t)n * 96 + t] = vnew;
    }
    vnewS[half][t] = vnew;
  }
  __syncthreads();
  if (t < 6 && active) {
    int i = t / 3, c = t - i * 3;
    float acc = 0.f;
#pragma unroll
    for (int vo = 0; vo < 32; ++vo) acc += vnewS[half][vo * 3 + c] * Wproj[vo * 2 + i];
    xout[(size_t)n * 6 + t] = acc;
  }
}

extern "C" void kernel_launch(void* const* d_in, const int* in_sizes, int n_in,
                              void* d_out, int out_size, void* d_ws, size_t ws_size,
                              hipStream_t stream) {
  const float* x = (const float*)d_in[0];
  const float* emb = (const float*)d_in[1];
  const float* Wup = (const float*)d_in[2];
  const float* Wproj = (const float*)d_in[3];
  const float* fc1 = (const float*)d_in[4];
  const float* b1 = (const float*)d_in[5];
  const float* fc2 = (const float*)d_in[6];
  const float* Wsv = (const float*)d_in[7];
  const float* Wvs = (const float*)d_in[8];
  const float* Wscs = (const float*)d_in[9];
  const float* Wscv = (const float*)d_in[10];
  const float* Ws = (const float*)d_in[11];
  const float* Wv = (const float*)d_in[12];
  const float* hArr = (const float*)d_in[13];
  const float* mixArr = (const float*)d_in[14];
  const int* nattr = (const int*)d_in[15];
  const int* esrc = (const int*)d_in[16];
  const int* edst = (const int*)d_in[17];

  const int N = in_sizes[0] / 6;
  const int E = in_sizes[16];

  float* ws = (float*)d_ws;
  size_t off = 0;
  auto alloc = [&](size_t nf) {
    float* p = ws + off;
    off += (nf + 3) & ~(size_t)3;
    return p;
  };
  float* sbuf = alloc((size_t)N * 64);
  float* sold = alloc((size_t)N * 64);
  float* vbuf = alloc((size_t)N * 96);
  float* vold = alloc((size_t)N * 96);
  float* xcur = alloc((size_t)N * 6);
  float* aggbuf = alloc((size_t)N * 192);
  float* Amat = alloc((size_t)cL * cNT * 64 * 96);
  float* Bmat = alloc((size_t)cL * cNT * 32 * 32);
  u16* fc2L = (u16*)alloc((size_t)cL * 6144);       // L*12288 bf16
  u16* WsvL = (u16*)alloc((size_t)cL * 2048);       // L*2*2048 bf16
  u16* WvsL = (u16*)alloc((size_t)cL * 3072);       // L*2*3072 bf16
  u16* fc1L = (u16*)alloc((size_t)cL * 1024);       // L*2048 bf16 (kq padded to 4)
  int* deg = (int*)alloc((size_t)(N + 4));
  int* row_ptr = (int*)alloc((size_t)(N + 4));
  int* cursor = (int*)alloc((size_t)(N + 4));
  int* esrc_s = (int*)alloc((size_t)E);
  int* edst_s = (int*)alloc((size_t)E);

  // init
  hipMemsetAsync(sbuf, 0, sizeof(float) * (size_t)N * 128, stream);  // sbuf + sold
  hipMemsetAsync(aggbuf, 0, sizeof(float) * (size_t)N * 192, stream);  // layer-0 agg
  k_init<<<(N * 32 + 255) / 256, 256, 0, stream>>>(x, Wup, vbuf, vold, xcur, N);
  k_precompA<<<(cL * cNT * 64 * 96 + 255) / 256, 256, 0, stream>>>(emb, Wscs, Amat);
  k_precompB<<<(cL * cNT * 32 * 32 + 255) / 256, 256, 0, stream>>>(emb, Wscv, Bmat);
  {
    int tot = cL * 12288 + cL * 4096 + cL * 6144 + cL * 2048;
    k_packB<<<(tot + 255) / 256, 256, 0, stream>>>(fc2, Wsv, Wvs, fc1, fc2L, WsvL, WvsL, fc1L);
  }
  k_zero_i<<<(N + 255) / 256, 256, 0, stream>>>(deg, N);
  k_hist<<<(E + 255) / 256, 256, 0, stream>>>(edst, deg, E);
  k_scan<<<1, 1024, 0, stream>>>(deg, row_ptr, cursor, N);
  k_scatter<<<(E + 255) / 256, 256, 0, stream>>>(esrc, edst, cursor, esrc_s, edst_s, E);

  int eblocks = (E + 63) / 64;
  int gblocks = (N + 1) / 2;
  for (int l = 0; l < cL; ++l) {
    if (l == 0)
      k_edge_mfma<true><<<eblocks, 128, 0, stream>>>(
          xcur, sbuf, vbuf, esrc_s, edst_s, fc1L + l * 2048, b1 + l * 64,
          fc2L + l * 12288, WsvL + l * 4096, WsvL + l * 4096 + 2048,
          WvsL + l * 6144, WvsL + l * 6144 + 3072, aggbuf, E);
    else
      k_edge_mfma<false><<<eblocks, 128, 0, stream>>>(
          xcur, sbuf, vbuf, esrc_s, edst_s, fc1L + l * 2048, b1 + l * 64,
          fc2L + l * 12288, WsvL + l * 4096, WsvL + l * 4096 + 2048,
          WvsL + l * 6144, WvsL + l * 6144 + 3072, aggbuf, E);
    float* xout = (l == cL - 1) ? (float*)d_out : xcur;
    if (l < cL - 1)
      k_gnode<true><<<gblocks, 256, 0, stream>>>(
          aggbuf, sbuf, sold, vbuf, vold, Amat + (size_t)l * cNT * 64 * 96,
          Bmat + (size_t)l * cNT * 1024, Ws + l * 4096, Wv + l * 1024, Wproj, nattr,
          hArr, mixArr, l, xout, N);
    else
      k_gnode<false><<<gblocks, 256, 0, stream>>>(
          aggbuf, sbuf, sold, vbuf, vold, Amat + (size_t)l * cNT * 64 * 96,
          Bmat + (size_t)l * cNT * 1024, Ws + l * 4096, Wv + l * 1024, Wproj, nattr,
          hArr, mixArr, l, xout, N);
  }
}

// Round 16
// 490.002 us; speedup vs baseline: 1.1312x; 1.0279x over previous
//
#include <hip/hip_runtime.h>
#include <math.h>

constexpr int cNS = 64, cNV = 32, cNB = 8, cL = 4, cEMB = 32, cNT = 10;
constexpr float PI_F = 3.14159265358979323846f;
constexpr float INV_SQRT_NN = 0.17677669529663687f;   // 1/sqrt(32)
constexpr float BESSEL_C = 2.3094010767585034f;       // sqrt(2/3)*sqrt(8)
constexpr float SQRT3 = 1.7320508075688772f;

// wb row stride in u16: 192 exactly. Swizzle col^xo only flips bits 3-4, so all
// swizzled cols stay <192 (max 167^24=191) — no slack needed. Per-block LDS
// 26,368 B -> 6 blocks/CU (vs 5 at WST=200). f-region at 4864..6144.
constexpr int WST = 192;
constexpr int FOFF = 4864;

typedef unsigned short u16;
typedef unsigned int u32;
typedef unsigned long long u64;
typedef __attribute__((ext_vector_type(8))) short bf16x8;
typedef __attribute__((ext_vector_type(4))) float f32x4;
typedef __attribute__((ext_vector_type(2))) float f32x2;
typedef __attribute__((ext_vector_type(4))) int i32x4;

__device__ __forceinline__ u16 f2b(float x) {   // f32 -> bf16 RNE (scalar fallback)
  u32 u = __float_as_uint(x);
  return (u16)((u + 0x7fffu + ((u >> 16) & 1u)) >> 16);
}
__device__ __forceinline__ float b2f(u16 h) { return __uint_as_float(((u32)h) << 16); }
__device__ __forceinline__ float blo(u32 w) { return __uint_as_float(w << 16); }
__device__ __forceinline__ float bhi(u32 w) { return __uint_as_float(w & 0xffff0000u); }

// HW packed f32->bf16 (2 values, 1 instruction)
__device__ __forceinline__ u32 pkbf(float lo, float hi) {
  u32 r;
  asm("v_cvt_pk_bf16_f32 %0, %1, %2" : "=v"(r) : "v"(lo), "v"(hi));
  return r;
}

// lgkmcnt(0) + hard scheduling fence (rule #18)
__device__ __forceinline__ void lds_fence() {
  asm volatile("s_waitcnt lgkmcnt(0)" ::: "memory");
  __builtin_amdgcn_sched_barrier(0);
}

union U8 { bf16x8 v; u32 w[4]; };

__device__ __forceinline__ f32x4 mfma16(bf16x8 a, bf16x8 b, f32x4 c) {
  return __builtin_amdgcn_mfma_f32_16x16x32_bf16(a, b, c, 0, 0, 0);
}

// ---------------- precompute kernels ----------------

__global__ void k_precompA(const float* __restrict__ emb, const float* __restrict__ Wss,
                           float* __restrict__ A) {
  int idx = blockIdx.x * 256 + threadIdx.x;
  if (idx >= cL * cNT * 64 * 96) return;
  int m = idx % 96;
  int u = (idx / 96) % 64;
  int t = (idx / (96 * 64)) % cNT;
  int l = idx / (96 * 64 * cNT);
  float acc = 0.f;
#pragma unroll
  for (int e = 0; e < 32; ++e)
    acc += emb[t * 32 + e] * Wss[((size_t)(l * 64 + u) * 32 + e) * 96 + m];
  A[idx] = acc;
}

__global__ void k_precompB(const float* __restrict__ emb, const float* __restrict__ Wsv_,
                           float* __restrict__ B) {
  int idx = blockIdx.x * 256 + threadIdx.x;
  if (idx >= cL * cNT * 32 * 32) return;
  int vo = idx % 32;
  int u = (idx / 32) % 32;
  int t = (idx / 1024) % cNT;
  int l = idx / (1024 * cNT);
  float acc = 0.f;
#pragma unroll
  for (int e = 0; e < 32; ++e)
    acc += emb[t * 32 + e] * Wsv_[((size_t)(l * 32 + u) * 32 + e) * 32 + vo];
  B[idx] = acc;
}

// pack fc2 / W_sv / W_vs / fc1 into bf16 MFMA-B layouts: BL[(k/8)*N*8 + n*8 + (k%8)]
__global__ void k_packB(const float* __restrict__ fc2, const float* __restrict__ Wsv,
                        const float* __restrict__ Wvs, const float* __restrict__ fc1,
                        u16* __restrict__ fc2L, u16* __restrict__ WsvL,
                        u16* __restrict__ WvsL, u16* __restrict__ fc1L) {
  int idx = blockIdx.x * 256 + threadIdx.x;
  const int T1 = cL * 12288, T2 = cL * 2 * 2048, T3 = cL * 2 * 3072, T4 = cL * 2048;
  if (idx < T1) {
    int l = idx / 12288, r = idx % 12288;
    int ki = r & 7, tt = r >> 3;
    int nn = tt % 192, kq = tt / 192;
    fc2L[idx] = f2b(fc2[((size_t)(l * 64) + kq * 8 + ki) * 192 + nn]);
  } else if (idx < T1 + T2) {
    int r0 = idx - T1;
    int l = r0 / 4096, r1 = r0 % 4096;
    int k2 = r1 / 2048, r = r1 % 2048;
    int ki = r & 7, tt = r >> 3;
    int mm = tt % 32, kq = tt / 32;
    WsvL[r0] = f2b(Wsv[((size_t)((l * 64 + kq * 8 + ki) * 2) + k2) * 32 + mm]);
  } else if (idx < T1 + T2 + T3) {
    int r0 = idx - T1 - T2;
    int l = r0 / 6144, r1 = r0 % 6144;
    int k2 = r1 / 3072, r = r1 % 3072;
    int ki = r & 7, tt = r >> 3;
    int mm = tt % 96, kq = tt / 96;
    WvsL[r0] = f2b(Wvs[((size_t)((l * 32 + kq * 8 + ki) * 2) + k2) * 96 + mm]);
  } else if (idx < T1 + T2 + T3 + T4) {
    int r0 = idx - T1 - T2 - T3;
    int l = r0 / 2048, r1 = r0 % 2048;
    int kq = r1 / 512, rem = r1 % 512;
    int n = rem / 8, ki = rem & 7;
    fc1L[r0] = (kq < 2) ? f2b(fc1[l * 1024 + (kq * 8 + ki) * 64 + n]) : (u16)0;
  }
}

__global__ void k_init(const float* __restrict__ x, const float* __restrict__ Wup,
                       float* __restrict__ v, float* __restrict__ v_old,
                       float* __restrict__ xcur, int N) {
  int idx = blockIdx.x * 256 + threadIdx.x;
  if (idx >= N * 32) return;
  int n = idx >> 5, vc = idx & 31;
  float w0 = Wup[vc], w1 = Wup[32 + vc];
#pragma unroll
  for (int c = 0; c < 3; ++c) {
    float val = x[n * 6 + c] * w0 + x[n * 6 + 3 + c] * w1;
    v[idx * 3 + c] = val;
    v_old[idx * 3 + c] = val;
  }
  if (vc < 6) xcur[n * 6 + vc] = x[n * 6 + vc];
}

// ---------------- CSR build ----------------

__global__ void k_zero_i(int* __restrict__ p, int n) {
  int i = blockIdx.x * 256 + threadIdx.x;
  if (i < n) p[i] = 0;
}

__global__ void k_hist(const int* __restrict__ edst, int* __restrict__ deg, int E) {
  int e = blockIdx.x * 256 + threadIdx.x;
  if (e < E) atomicAdd(&deg[edst[e]], 1);
}

__global__ __launch_bounds__(1024) void k_scan(const int* __restrict__ deg,
                                               int* __restrict__ row_ptr,
                                               int* __restrict__ cursor, int N) {
  __shared__ int part[1024];
  int t = threadIdx.x;
  int chunk = (N + 1023) / 1024;
  int base = t * chunk;
  int sum = 0;
  for (int i = 0; i < chunk; ++i) {
    int idx = base + i;
    if (idx < N) sum += deg[idx];
  }
  part[t] = sum;
  __syncthreads();
  for (int off = 1; off < 1024; off <<= 1) {
    int val = (t >= off) ? part[t - off] : 0;
    __syncthreads();
    part[t] += val;
    __syncthreads();
  }
  int run = (t > 0) ? part[t - 1] : 0;
  for (int i = 0; i < chunk; ++i) {
    int idx = base + i;
    if (idx < N) {
      row_ptr[idx] = run;
      cursor[idx] = run;
      run += deg[idx];
    }
  }
  if (t == 1023) row_ptr[N] = part[1023];
}

__global__ void k_scatter(const int* __restrict__ esrc, const int* __restrict__ edst,
                          int* __restrict__ cursor, int* __restrict__ esrc_s,
                          int* __restrict__ edst_s, int E) {
  int e = blockIdx.x * 256 + threadIdx.x;
  if (e < E) {
    int d = edst[e];
    int p = atomicAdd(&cursor[d], 1);
    esrc_s[p] = esrc[e];
    edst_s[p] = d;
  }
}

// ---------------- fused MFMA edge kernel: wave = 32 consecutive CSR-sorted edges ----
// Aggregation fused: per-wave segmented reduction over dst runs, atomicAdd f32 into
// agg[N][192] (cols 0..95 = msg_s[m]; 96 + c*32 + m' = msg_v). No msgbuf round-trip.
// Round-16: WST 200->192 ONLY (occupancy 5->6 blocks/CU); no setprio (round-14 lesson).
template <bool SZERO>
__global__ __launch_bounds__(128) void k_edge_mfma(
    const float* __restrict__ xcur, const float* __restrict__ s, const float* __restrict__ v,
    const int* __restrict__ esrc_s, const int* __restrict__ edst_s,
    const u16* __restrict__ fc1L, const float* __restrict__ b1,
    const u16* __restrict__ fc2L, const u16* __restrict__ WsvL0,
    const u16* __restrict__ WsvL1, const u16* __restrict__ WvsL0,
    const u16* __restrict__ WvsL1, float* __restrict__ aggbuf, int E) {
  __shared__ u16 wbAll[2][32 * WST];
  __shared__ float aAll[2][32][6];
  __shared__ int dAll[2][32];
  int wid = threadIdx.x >> 6, lane = threadIdx.x & 63;
  int e0 = (blockIdx.x * 2 + wid) * 32;
  if (e0 >= E) return;
  u16* wb = wbAll[wid];
  int lrow = lane & 15, lg = lane >> 4;

  // ====== geometry: lane = (el = lane>>1, qq = lane&1); one (edge, vec) per lane ======
  {
    int el = lane >> 1, qq = lane & 1;
    int ge = e0 + el;
    if (ge >= E) ge = E - 1;
    int gs = esrc_s[ge], gd = edst_s[ge];
    const float* ps = xcur + (size_t)gs * 6 + qq * 3;
    const float* pd = xcur + (size_t)gd * 6 + qq * 3;
    float vx = ps[0] - pd[0];
    float vy = ps[1] - pd[1];
    float vz = ps[2] - pd[2];
    float r2 = vx * vx + vy * vy + vz * vz;
    float rr = sqrtf(r2);
    float invr = 1.0f / rr;
    float th = (PI_F / 3.0f) * rr;
    float s1, c1;
    __sincosf(th, &s1, &c1);
    float twc = 2.0f * c1;
    float snm = 0.f, sn = s1;
    float fc = BESSEL_C * invr;
    float f8[8];
#pragma unroll
    for (int nn = 0; nn < 8; ++nn) {
      f8[nn] = fc * sn;
      float nx = twc * sn - snm;
      snm = sn;
      sn = nx;
    }
    float uu = (2.0f / 3.0f) * rr - 2.0f;
    float cut;
    if (uu > 0.f) cut = 0.f;
    else if (uu < -1.f) cut = 1.f;
    else cut = (1.0f - __cosf(PI_F * uu)) * 0.5f;
    float sc = cut * SQRT3 * invr;
    // f region: offset FOFF, 32 rows x 40 u16 (cols 0..15 data, 16..31 zero, 32..39 pad)
    u32* fp = (u32*)(wb + FOFF + el * 40);
#pragma unroll
    for (int i = 0; i < 4; ++i) fp[qq * 4 + i] = pkbf(f8[2 * i], f8[2 * i + 1]);
#pragma unroll
    for (int i = 0; i < 4; ++i) fp[8 + qq * 4 + i] = 0u;
    float* ap = aAll[wid][el];
    ap[qq * 3 + 0] = vx * sc;
    ap[qq * 3 + 1] = vy * sc;
    ap[qq * 3 + 2] = vz * sc;
    if (qq == 0) dAll[wid][el] = gd;
  }
  lds_fence();

  // ====== MLP: hid[32][64] = silu(f @ fc1 + b1) via 8 MFMA (B shared across halves) ====
  {
    bf16x8 fA0 = *(const bf16x8*)(wb + FOFF + lrow * 40 + lg * 8);
    bf16x8 fA1 = *(const bf16x8*)(wb + FOFF + (16 + lrow) * 40 + lg * 8);
    f32x4 hp0[4], hp1[4];
#pragma unroll
    for (int nb = 0; nb < 4; ++nb) {
      bf16x8 bB = *(const bf16x8*)(fc1L + (size_t)(lg * 64 + nb * 16 + lrow) * 8);
      f32x4 z = {0.f, 0.f, 0.f, 0.f};
      hp0[nb] = mfma16(fA0, bB, z);
      hp1[nb] = mfma16(fA1, bB, z);
    }
#pragma unroll
    for (int nb = 0; nb < 4; ++nb) {
      float bias = b1[nb * 16 + lrow];
      int col = nb * 16 + lrow;
      {
        float hv[4];
#pragma unroll
        for (int r = 0; r < 4; ++r) {
          float xv = hp0[nb][r] + bias;
          hv[r] = xv * (1.0f / (1.0f + __expf(-xv)));
        }
        u32 p01 = pkbf(hv[0], hv[1]);
        u32 p23 = pkbf(hv[2], hv[3]);
        wb[(4 * lg + 0) * 72 + col] = (u16)p01;
        wb[(4 * lg + 1) * 72 + col] = (u16)(p01 >> 16);
        wb[(4 * lg + 2) * 72 + col] = (u16)p23;
        wb[(4 * lg + 3) * 72 + col] = (u16)(p23 >> 16);
      }
      {
        float hv[4];
#pragma unroll
        for (int r = 0; r < 4; ++r) {
          float xv = hp1[nb][r] + bias;
          hv[r] = xv * (1.0f / (1.0f + __expf(-xv)));
        }
        u32 p01 = pkbf(hv[0], hv[1]);
        u32 p23 = pkbf(hv[2], hv[3]);
        wb[(16 + 4 * lg + 0) * 72 + col] = (u16)p01;
        wb[(16 + 4 * lg + 1) * 72 + col] = (u16)(p01 >> 16);
        wb[(16 + 4 * lg + 2) * 72 + col] = (u16)p23;
        wb[(16 + 4 * lg + 3) * 72 + col] = (u16)(p23 >> 16);
      }
    }
  }
  lds_fence();

  // hid A-fragments (both halves)
  bf16x8 ha0 = *(const bf16x8*)(wb + lrow * 72 + lg * 8);
  bf16x8 hbf0 = *(const bf16x8*)(wb + lrow * 72 + 32 + lg * 8);
  bf16x8 ha1 = *(const bf16x8*)(wb + (16 + lrow) * 72 + lg * 8);
  bf16x8 hbf1 = *(const bf16x8*)(wb + (16 + lrow) * 72 + 32 + lg * 8);
  lds_fence();   // reads done before wb overwrite

  // ---- GEMM2: w[32,192] = hid @ fc2, B-frags shared across halves; swizzled store
  int xw = lg << 3;
#pragma unroll
  for (int nb = (SZERO ? 8 : 0); nb < 12; ++nb) {
    bf16x8 b0 = *(const bf16x8*)(fc2L + (size_t)(lg * 192 + nb * 16 + lrow) * 8);
    bf16x8 b1v = *(const bf16x8*)(fc2L + (size_t)((4 + lg) * 192 + nb * 16 + lrow) * 8);
    f32x4 z = {0.f, 0.f, 0.f, 0.f};
    f32x4 c0 = mfma16(ha0, b0, z);
    c0 = mfma16(hbf0, b1v, c0);
    f32x4 c1 = mfma16(ha1, b0, z);
    c1 = mfma16(hbf1, b1v, c1);
    int n = nb * 16 + lrow;
    int pn = (n < 128) ? ((n & 1) * 64 + (n >> 1)) : (128 + (n & 1) * 32 + ((n - 128) >> 1));
    int cx = pn ^ xw;
    {
      int rb = (4 * lg) * WST + cx;
      u32 p01 = pkbf(c0[0], c0[1]);
      u32 p23 = pkbf(c0[2], c0[3]);
      wb[rb] = (u16)p01;
      wb[rb + WST] = (u16)(p01 >> 16);
      wb[rb + 2 * WST] = (u16)p23;
      wb[rb + 3 * WST] = (u16)(p23 >> 16);
    }
    {
      int rb = (16 + 4 * lg) * WST + cx;
      u32 p01 = pkbf(c1[0], c1[1]);
      u32 p23 = pkbf(c1[2], c1[3]);
      wb[rb] = (u16)p01;
      wb[rb + WST] = (u16)(p01 >> 16);
      wb[rb + 2 * WST] = (u16)p23;
      wb[rb + 3 * WST] = (u16)(p23 >> 16);
    }
  }
  lds_fence();

  // swizzled row pointers (offsets used below are multiples of 32 -> swizzle-safe)
  const u16* wrow0 = wb + lrow * WST + (((lg ^ (lrow >> 2)) & 3) << 3);
  const u16* wrow1 = wrow0 + 16 * WST;

  int prow0 = e0 + lrow;
  if (prow0 >= E) prow0 = E - 1;
  int prow1 = e0 + 16 + lrow;
  if (prow1 >= E) prow1 = E - 1;
  int srcs[2] = {esrc_s[prow0], esrc_s[prow1]};

  // ---- Q path: T = s_src (.) w1 ; Q = T @ W_sv (B-frags shared across halves)
  f32x4 q0[2][2], q1[2][2];
  if (!SZERO) {
    U8 t0a[2], t0b[2], t1a[2], t1b[2];
#pragma unroll
    for (int h = 0; h < 2; ++h) {
      const u16* wr = h ? wrow1 : wrow0;
      const float* sp = s + (size_t)srcs[h] * 64;
      float sv0[8], sv1[8];
      *(f32x4*)(sv0) = *(const f32x4*)(sp + lg * 8);
      *(f32x4*)(sv0 + 4) = *(const f32x4*)(sp + lg * 8 + 4);
      *(f32x4*)(sv1) = *(const f32x4*)(sp + 32 + lg * 8);
      *(f32x4*)(sv1 + 4) = *(const f32x4*)(sp + 32 + lg * 8 + 4);
      i32x4 W0a = *(const i32x4*)(wr);
      i32x4 W0b = *(const i32x4*)(wr + 32);
      i32x4 W1a = *(const i32x4*)(wr + 64);
      i32x4 W1b = *(const i32x4*)(wr + 96);
#pragma unroll
      for (int j2 = 0; j2 < 4; ++j2) {
        u32 wa = (u32)W0a[j2], wbv = (u32)W0b[j2], wc = (u32)W1a[j2], wd = (u32)W1b[j2];
        t0a[h].w[j2] = pkbf(sv0[2 * j2] * blo(wa), sv0[2 * j2 + 1] * bhi(wa));
        t0b[h].w[j2] = pkbf(sv1[2 * j2] * blo(wbv), sv1[2 * j2 + 1] * bhi(wbv));
        t1a[h].w[j2] = pkbf(sv0[2 * j2] * blo(wc), sv0[2 * j2 + 1] * bhi(wc));
        t1b[h].w[j2] = pkbf(sv1[2 * j2] * blo(wd), sv1[2 * j2 + 1] * bhi(wd));
      }
    }
#pragma unroll
    for (int nb = 0; nb < 2; ++nb) {
      bf16x8 bA = *(const bf16x8*)(WsvL0 + (size_t)(lg * 32 + nb * 16 + lrow) * 8);
      bf16x8 bB = *(const bf16x8*)(WsvL0 + (size_t)((4 + lg) * 32 + nb * 16 + lrow) * 8);
      bf16x8 bC = *(const bf16x8*)(WsvL1 + (size_t)(lg * 32 + nb * 16 + lrow) * 8);
      bf16x8 bD = *(const bf16x8*)(WsvL1 + (size_t)((4 + lg) * 32 + nb * 16 + lrow) * 8);
#pragma unroll
      for (int h = 0; h < 2; ++h) {
        f32x4 z = {0.f, 0.f, 0.f, 0.f};
        f32x4 c = mfma16(t0a[h].v, bA, z);
        c = mfma16(t0b[h].v, bB, c);
        q0[h][nb] = c;
        f32x4 c2 = mfma16(t1a[h].v, bC, z);
        c2 = mfma16(t1b[h].v, bD, c2);
        q1[h][nb] = c2;
      }
    }
  }

  // ---- M path: G = (v_src . a) (.) w2 ; msg_s = G @ Wvs (B-frags shared)
  U8 ga[2], gb[2];
#pragma unroll
  for (int h = 0; h < 2; ++h) {
    const float* ap = aAll[wid][h * 16 + lrow];
    float a00 = ap[0], a01 = ap[1], a02 = ap[2], a10 = ap[3], a11 = ap[4], a12 = ap[5];
    float vl[24];
    const float* vp = v + (size_t)srcs[h] * 96 + lg * 24;
#pragma unroll
    for (int i = 0; i < 6; ++i) *(f32x4*)(vl + 4 * i) = *(const f32x4*)(vp + 4 * i);
    const u16* wr = h ? wrow1 : wrow0;
    i32x4 W2a = *(const i32x4*)(wr + 128);
    i32x4 W2b = *(const i32x4*)(wr + 160);
#pragma unroll
    for (int j2 = 0; j2 < 4; ++j2) {
      float d0a, d1a, d0b, d1b;
      {
        float vx = vl[6 * j2 + 0], vy = vl[6 * j2 + 1], vz = vl[6 * j2 + 2];
        d0a = vx * a00 + vy * a01 + vz * a02;
        d1a = vx * a10 + vy * a11 + vz * a12;
      }
      {
        float vx = vl[6 * j2 + 3], vy = vl[6 * j2 + 4], vz = vl[6 * j2 + 5];
        d0b = vx * a00 + vy * a01 + vz * a02;
        d1b = vx * a10 + vy * a11 + vz * a12;
      }
      u32 wa = (u32)W2a[j2], wbv = (u32)W2b[j2];
      ga[h].w[j2] = pkbf(d0a * blo(wa), d0b * bhi(wa));
      gb[h].w[j2] = pkbf(d1a * blo(wbv), d1b * bhi(wbv));
    }
  }
  f32x4 mS[2][6];
#pragma unroll
  for (int nb = 0; nb < 6; ++nb) {
    bf16x8 b0 = *(const bf16x8*)(WvsL0 + (size_t)(lg * 96 + nb * 16 + lrow) * 8);
    bf16x8 b1v = *(const bf16x8*)(WvsL1 + (size_t)(lg * 96 + nb * 16 + lrow) * 8);
#pragma unroll
    for (int h = 0; h < 2; ++h) {
      f32x4 z = {0.f, 0.f, 0.f, 0.f};
      f32x4 c = mfma16(ga[h].v, b0, z);
      c = mfma16(gb[h].v, b1v, c);
      mS[h][nb] = c;
    }
  }

  // ---- stage final msg rows into wb (overwrite w; swizzled)
  lds_fence();
#pragma unroll
  for (int h = 0; h < 2; ++h) {
    int rbase = (h * 16 + 4 * lg) * WST;
#pragma unroll
    for (int nb = 0; nb < 6; ++nb) {
      u32 p01 = pkbf(mS[h][nb][0], mS[h][nb][1]);
      u32 p23 = pkbf(mS[h][nb][2], mS[h][nb][3]);
      int colx = (nb * 16 + lrow) ^ xw;
      wb[rbase + colx] = (u16)p01;
      wb[rbase + WST + colx] = (u16)(p01 >> 16);
      wb[rbase + 2 * WST + colx] = (u16)p23;
      wb[rbase + 3 * WST + colx] = (u16)(p23 >> 16);
    }
    if (!SZERO) {
#pragma unroll
      for (int nb = 0; nb < 2; ++nb) {
#pragma unroll
        for (int r = 0; r < 4; ++r) {
          int el = h * 16 + 4 * lg + r;
          const float* ap = aAll[wid][el];
          float Q0v = q0[h][nb][r], Q1v = q1[h][nb][r];
          float v0 = Q0v * ap[0] + Q1v * ap[3];
          float v1 = Q0v * ap[1] + Q1v * ap[4];
          float v2 = Q0v * ap[2] + Q1v * ap[5];
          u32 p01 = pkbf(v0, v1);
          int base = el * WST + ((96 + nb * 16 + lrow) ^ xw);
          wb[base] = (u16)p01;
          wb[base + 32] = (u16)(p01 >> 16);
          wb[base + 64] = f2b(v2);
        }
      }
    }
  }
  lds_fence();

  // ---- segmented reduction over dst runs (edges sorted by dst) + atomicAdd ----
  {
    int nrows = E - e0;
    if (nrows > 32) nrows = 32;
    const int* dstv = dAll[wid];
    int c0 = lane, c1 = lane + 64, c2 = lane + 128;
    bool v1ok = SZERO ? (c1 < 96) : true;
    bool v2ok = SZERO ? false : true;
    float acc0 = 0.f, acc1 = 0.f, acc2 = 0.f;
    int prev = dstv[0];
    for (int r = 0; r < nrows; ++r) {
      int d = dstv[r];
      if (d != prev) {   // wave-uniform branch
        float* ab = aggbuf + (size_t)prev * 192;
        atomicAdd(ab + c0, acc0);
        if (v1ok) atomicAdd(ab + c1, acc1);
        if (v2ok) atomicAdd(ab + c2, acc2);
        acc0 = acc1 = acc2 = 0.f;
        prev = d;
      }
      int xo = ((r >> 2) & 3) << 3;
      int rb = r * WST;
      acc0 += b2f(wb[rb + (c0 ^ xo)]);
      if (v1ok) acc1 += b2f(wb[rb + (c1 ^ xo)]);
      if (v2ok) acc2 += b2f(wb[rb + (c2 ^ xo)]);
    }
    float* ab = aggbuf + (size_t)prev * 192;
    atomicAdd(ab + c0, acc0);
    if (v1ok) atomicAdd(ab + c1, acc1);
    if (v2ok) atomicAdd(ab + c2, acc2);
  }
}

// ---------------- node update (2 nodes per 256-thread block; reads dense agg) ------
// ZERO_AGG: after reading agg, write zeros back so the next layer needs no memset.
template <bool ZERO_AGG>
__global__ __launch_bounds__(256) void k_gnode(
    float* __restrict__ aggbuf,
    float* __restrict__ s, float* __restrict__ sold, float* __restrict__ v,
    float* __restrict__ vold,
    const float* __restrict__ Amat, const float* __restrict__ Bmat,
    const float* __restrict__ Ws, const float* __restrict__ Wv,
    const float* __restrict__ Wproj, const int* __restrict__ nattr,
    const float* __restrict__ hArr, const float* __restrict__ mixArr, int layer,
    float* __restrict__ xout, int N) {
  int half = threadIdx.x >> 7;
  int t = threadIdx.x & 127;
  int n = blockIdx.x * 2 + half;
  bool active = n < N;
  if (!active) n = N - 1;
  __shared__ float agg[2][192];
  __shared__ float srow[2][64];
  __shared__ float vrow[2][96];
  __shared__ float gateS[2][32];
  __shared__ float vnewS[2][96];
  if (t < 96) {
    agg[half][t] = aggbuf[(size_t)n * 192 + t] * INV_SQRT_NN;
    agg[half][96 + t] = aggbuf[(size_t)n * 192 + 96 + t] * INV_SQRT_NN;
    if (ZERO_AGG && active) {
      aggbuf[(size_t)n * 192 + t] = 0.f;
      aggbuf[(size_t)n * 192 + 96 + t] = 0.f;
    }
  }
  if (t < 64) srow[half][t] = s[(size_t)n * 64 + t];
  if (t < 96) vrow[half][t] = v[(size_t)n * 96 + t];
  __syncthreads();
  int type = nattr[n];
  float hv = hArr[layer];
  float h2v = hv * hv;
  float mx = mixArr[layer];
  float cs = 0.f;
  if (t < 96) {
    cs = agg[half][t];
    const float* Ac = Amat + (size_t)type * 64 * 96 + t;
#pragma unroll 8
    for (int u = 0; u < 64; ++u) cs += srow[half][u] * Ac[u * 96];
  }
  if (t >= 64 && t < 96) gateS[half][t - 64] = 1.0f / (1.0f + __expf(-cs));
  __syncthreads();
  if (t < 64) {
    float gs = cs * (1.0f / (1.0f + __expf(-cs)));
    float sis = 0.f;
#pragma unroll 8
    for (int u = 0; u < 64; ++u) sis += srow[half][u] * Ws[u * 64 + t];
    float scur = srow[half][t];
    float sprev = sold[(size_t)n * 64 + t];
    float snew = 2.f * scur - sprev + h2v * (mx * gs + (mx - 1.f) * sis);
    if (active) {
      sold[(size_t)n * 64 + t] = scur;
      s[(size_t)n * 64 + t] = snew;
    }
  }
  if (t < 96) {
    int vch = t / 3, c = t - vch * 3;
    float cv = agg[half][96 + c * 32 + vch];
    const float* Bc = Bmat + (size_t)type * 1024 + vch;
    float scv = 0.f, siv = 0.f;
#pragma unroll 8
    for (int u = 0; u < 32; ++u) {
      float vu = vrow[half][u * 3 + c];
      scv += vu * Bc[u * 32];
      siv += vu * Wv[u * 32 + vch];
    }
    cv += scv;
    float gv = cv * gateS[half][vch];
    float vcur = vrow[half][t];
    float vprev = vold[(size_t)n * 96 + t];
    float vnew = 2.f * vcur - vprev + h2v * (mx * gv + (mx - 1.f) * siv);
    if (active) {
      vold[(size_t)n * 96 + t] = vcur;
      v[(size_t)n * 96 + t] = vnew;
    }
    vnewS[half][t] = vnew;
  }
  __syncthreads();
  if (t < 6 && active) {
    int i = t / 3, c = t - i * 3;
    float acc = 0.f;
#pragma unroll
    for (int vo = 0; vo < 32; ++vo) acc += vnewS[half][vo * 3 + c] * Wproj[vo * 2 + i];
    xout[(size_t)n * 6 + t] = acc;
  }
}

extern "C" void kernel_launch(void* const* d_in, const int* in_sizes, int n_in,
                              void* d_out, int out_size, void* d_ws, size_t ws_size,
                              hipStream_t stream) {
  const float* x = (const float*)d_in[0];
  const float* emb = (const float*)d_in[1];
  const float* Wup = (const float*)d_in[2];
  const float* Wproj = (const float*)d_in[3];
  const float* fc1 = (const float*)d_in[4];
  const float* b1 = (const float*)d_in[5];
  const float* fc2 = (const float*)d_in[6];
  const float* Wsv = (const float*)d_in[7];
  const float* Wvs = (const float*)d_in[8];
  const float* Wscs = (const float*)d_in[9];
  const float* Wscv = (const float*)d_in[10];
  const float* Ws = (const float*)d_in[11];
  const float* Wv = (const float*)d_in[12];
  const float* hArr = (const float*)d_in[13];
  const float* mixArr = (const float*)d_in[14];
  const int* nattr = (const int*)d_in[15];
  const int* esrc = (const int*)d_in[16];
  const int* edst = (const int*)d_in[17];

  const int N = in_sizes[0] / 6;
  const int E = in_sizes[16];

  float* ws = (float*)d_ws;
  size_t off = 0;
  auto alloc = [&](size_t nf) {
    float* p = ws + off;
    off += (nf + 3) & ~(size_t)3;
    return p;
  };
  float* sbuf = alloc((size_t)N * 64);
  float* sold = alloc((size_t)N * 64);
  float* vbuf = alloc((size_t)N * 96);
  float* vold = alloc((size_t)N * 96);
  float* xcur = alloc((size_t)N * 6);
  float* aggbuf = alloc((size_t)N * 192);
  float* Amat = alloc((size_t)cL * cNT * 64 * 96);
  float* Bmat = alloc((size_t)cL * cNT * 32 * 32);
  u16* fc2L = (u16*)alloc((size_t)cL * 6144);       // L*12288 bf16
  u16* WsvL = (u16*)alloc((size_t)cL * 2048);       // L*2*2048 bf16
  u16* WvsL = (u16*)alloc((size_t)cL * 3072);       // L*2*3072 bf16
  u16* fc1L = (u16*)alloc((size_t)cL * 1024);       // L*2048 bf16 (kq padded to 4)
  int* deg = (int*)alloc((size_t)(N + 4));
  int* row_ptr = (int*)alloc((size_t)(N + 4));
  int* cursor = (int*)alloc((size_t)(N + 4));
  int* esrc_s = (int*)alloc((size_t)E);
  int* edst_s = (int*)alloc((size_t)E);

  // init
  hipMemsetAsync(sbuf, 0, sizeof(float) * (size_t)N * 128, stream);  // sbuf + sold
  hipMemsetAsync(aggbuf, 0, sizeof(float) * (size_t)N * 192, stream);  // layer-0 agg
  k_init<<<(N * 32 + 255) / 256, 256, 0, stream>>>(x, Wup, vbuf, vold, xcur, N);
  k_precompA<<<(cL * cNT * 64 * 96 + 255) / 256, 256, 0, stream>>>(emb, Wscs, Amat);
  k_precompB<<<(cL * cNT * 32 * 32 + 255) / 256, 256, 0, stream>>>(emb, Wscv, Bmat);
  {
    int tot = cL * 12288 + cL * 4096 + cL * 6144 + cL * 2048;
    k_packB<<<(tot + 255) / 256, 256, 0, stream>>>(fc2, Wsv, Wvs, fc1, fc2L, WsvL, WvsL, fc1L);
  }
  k_zero_i<<<(N + 255) / 256, 256, 0, stream>>>(deg, N);
  k_hist<<<(E + 255) / 256, 256, 0, stream>>>(edst, deg, E);
  k_scan<<<1, 1024, 0, stream>>>(deg, row_ptr, cursor, N);
  k_scatter<<<(E + 255) / 256, 256, 0, stream>>>(esrc, edst, cursor, esrc_s, edst_s, E);

  int eblocks = (E + 63) / 64;
  int gblocks = (N + 1) / 2;
  for (int l = 0; l < cL; ++l) {
    if (l == 0)
      k_edge_mfma<true><<<eblocks, 128, 0, stream>>>(
          xcur, sbuf, vbuf, esrc_s, edst_s, fc1L + l * 2048, b1 + l * 64,
          fc2L + l * 12288, WsvL + l * 4096, WsvL + l * 4096 + 2048,
          WvsL + l * 6144, WvsL + l * 6144 + 3072, aggbuf, E);
    else
      k_edge_mfma<false><<<eblocks, 128, 0, stream>>>(
          xcur, sbuf, vbuf, esrc_s, edst_s, fc1L + l * 2048, b1 + l * 64,
          fc2L + l * 12288, WsvL + l * 4096, WsvL + l * 4096 + 2048,
          WvsL + l * 6144, WvsL + l * 6144 + 3072, aggbuf, E);
    float* xout = (l == cL - 1) ? (float*)d_out : xcur;
    if (l < cL - 1)
      k_gnode<true><<<gblocks, 256, 0, stream>>>(
          aggbuf, sbuf, sold, vbuf, vold, Amat + (size_t)l * cNT * 64 * 96,
          Bmat + (size_t)l * cNT * 1024, Ws + l * 4096, Wv + l * 1024, Wproj, nattr,
          hArr, mixArr, l, xout, N);
    else
      k_gnode<false><<<gblocks, 256, 0, stream>>>(
          aggbuf, sbuf, sold, vbuf, vold, Amat + (size_t)l * cNT * 64 * 96,
          Bmat + (size_t)l * cNT * 1024, Ws + l * 4096, Wv + l * 1024, Wproj, nattr,
          hArr, mixArr, l, xout, N);
  }
}

// Round 17
// 485.296 us; speedup vs baseline: 1.1421x; 1.0097x over previous
//
#include <hip/hip_runtime.h>
#include <math.h>

constexpr int cNS = 64, cNV = 32, cNB = 8, cL = 4, cEMB = 32, cNT = 10;
constexpr float PI_F = 3.14159265358979323846f;
constexpr float INV_SQRT_NN = 0.17677669529663687f;   // 1/sqrt(32)
constexpr float BESSEL_C = 2.3094010767585034f;       // sqrt(2/3)*sqrt(8)
constexpr float SQRT3 = 1.7320508075688772f;

// wb row stride in u16: 192 exactly (round-16 winner: 6 blocks/CU).
constexpr int WST = 192;
constexpr int FOFF = 4864;

typedef unsigned short u16;
typedef unsigned int u32;
typedef unsigned long long u64;
typedef __attribute__((ext_vector_type(8))) short bf16x8;
typedef __attribute__((ext_vector_type(4))) float f32x4;
typedef __attribute__((ext_vector_type(2))) float f32x2;
typedef __attribute__((ext_vector_type(4))) int i32x4;

__device__ __forceinline__ u16 f2b(float x) {   // f32 -> bf16 RNE (scalar fallback)
  u32 u = __float_as_uint(x);
  return (u16)((u + 0x7fffu + ((u >> 16) & 1u)) >> 16);
}
__device__ __forceinline__ float b2f(u16 h) { return __uint_as_float(((u32)h) << 16); }
__device__ __forceinline__ float blo(u32 w) { return __uint_as_float(w << 16); }
__device__ __forceinline__ float bhi(u32 w) { return __uint_as_float(w & 0xffff0000u); }

// HW packed f32->bf16 (2 values, 1 instruction)
__device__ __forceinline__ u32 pkbf(float lo, float hi) {
  u32 r;
  asm("v_cvt_pk_bf16_f32 %0, %1, %2" : "=v"(r) : "v"(lo), "v"(hi));
  return r;
}

// lgkmcnt(0) + hard scheduling fence (rule #18)
__device__ __forceinline__ void lds_fence() {
  asm volatile("s_waitcnt lgkmcnt(0)" ::: "memory");
  __builtin_amdgcn_sched_barrier(0);
}

union U8 { bf16x8 v; u32 w[4]; };

__device__ __forceinline__ f32x4 mfma16(bf16x8 a, bf16x8 b, f32x4 c) {
  return __builtin_amdgcn_mfma_f32_16x16x32_bf16(a, b, c, 0, 0, 0);
}

// ---------------- merged precompute kernel ----------------
// One launch: A (emb x W_sc_s), B (emb x W_sc_v), and all bf16 weight packing.
__global__ void k_prep(const float* __restrict__ emb, const float* __restrict__ Wss,
                       const float* __restrict__ Wsv_, const float* __restrict__ fc2,
                       const float* __restrict__ Wsv, const float* __restrict__ Wvs,
                       const float* __restrict__ fc1, float* __restrict__ A,
                       float* __restrict__ B, u16* __restrict__ fc2L,
                       u16* __restrict__ WsvL, u16* __restrict__ WvsL,
                       u16* __restrict__ fc1L) {
  const int TOTA = cL * cNT * 64 * 96;            // 245760
  const int TOTB = cL * cNT * 32 * 32;            // 40960
  const int T1 = cL * 12288, T2 = cL * 2 * 2048, T3 = cL * 2 * 3072, T4 = cL * 2048;
  int idx = blockIdx.x * 256 + threadIdx.x;
  if (idx < TOTA) {
    int m = idx % 96;
    int u = (idx / 96) % 64;
    int t = (idx / (96 * 64)) % cNT;
    int l = idx / (96 * 64 * cNT);
    float acc = 0.f;
#pragma unroll
    for (int e = 0; e < 32; ++e)
      acc += emb[t * 32 + e] * Wss[((size_t)(l * 64 + u) * 32 + e) * 96 + m];
    A[idx] = acc;
    return;
  }
  idx -= TOTA;
  if (idx < TOTB) {
    int vo = idx % 32;
    int u = (idx / 32) % 32;
    int t = (idx / 1024) % cNT;
    int l = idx / (1024 * cNT);
    float acc = 0.f;
#pragma unroll
    for (int e = 0; e < 32; ++e)
      acc += emb[t * 32 + e] * Wsv_[((size_t)(l * 32 + u) * 32 + e) * 32 + vo];
    B[idx] = acc;
    return;
  }
  idx -= TOTB;
  if (idx < T1) {
    int l = idx / 12288, r = idx % 12288;
    int ki = r & 7, tt = r >> 3;
    int nn = tt % 192, kq = tt / 192;
    fc2L[idx] = f2b(fc2[((size_t)(l * 64) + kq * 8 + ki) * 192 + nn]);
  } else if (idx < T1 + T2) {
    int r0 = idx - T1;
    int l = r0 / 4096, r1 = r0 % 4096;
    int k2 = r1 / 2048, r = r1 % 2048;
    int ki = r & 7, tt = r >> 3;
    int mm = tt % 32, kq = tt / 32;
    WsvL[r0] = f2b(Wsv[((size_t)((l * 64 + kq * 8 + ki) * 2) + k2) * 32 + mm]);
  } else if (idx < T1 + T2 + T3) {
    int r0 = idx - T1 - T2;
    int l = r0 / 6144, r1 = r0 % 6144;
    int k2 = r1 / 3072, r = r1 % 3072;
    int ki = r & 7, tt = r >> 3;
    int mm = tt % 96, kq = tt / 96;
    WvsL[r0] = f2b(Wvs[((size_t)((l * 32 + kq * 8 + ki) * 2) + k2) * 96 + mm]);
  } else if (idx < T1 + T2 + T3 + T4) {
    int r0 = idx - T1 - T2 - T3;
    int l = r0 / 2048, r1 = r0 % 2048;
    int kq = r1 / 512, rem = r1 % 512;
    int n = rem / 8, ki = rem & 7;
    fc1L[r0] = (kq < 2) ? f2b(fc1[l * 1024 + (kq * 8 + ki) * 64 + n]) : (u16)0;
  }
}

__global__ void k_init(const float* __restrict__ x, const float* __restrict__ Wup,
                       float* __restrict__ v, float* __restrict__ v_old,
                       float* __restrict__ xcur, int N) {
  int idx = blockIdx.x * 256 + threadIdx.x;
  if (idx >= N * 32) return;
  int n = idx >> 5, vc = idx & 31;
  float w0 = Wup[vc], w1 = Wup[32 + vc];
#pragma unroll
  for (int c = 0; c < 3; ++c) {
    float val = x[n * 6 + c] * w0 + x[n * 6 + 3 + c] * w1;
    v[idx * 3 + c] = val;
    v_old[idx * 3 + c] = val;
  }
  if (vc < 6) xcur[n * 6 + vc] = x[n * 6 + vc];
}

// ---------------- CSR build ----------------

__global__ void k_hist(const int* __restrict__ edst, int* __restrict__ deg, int E) {
  int e = blockIdx.x * 256 + threadIdx.x;
  if (e < E) atomicAdd(&deg[edst[e]], 1);
}

__global__ __launch_bounds__(1024) void k_scan(const int* __restrict__ deg,
                                               int* __restrict__ row_ptr,
                                               int* __restrict__ cursor, int N) {
  __shared__ int part[1024];
  int t = threadIdx.x;
  int chunk = (N + 1023) / 1024;
  int base = t * chunk;
  int sum = 0;
  for (int i = 0; i < chunk; ++i) {
    int idx = base + i;
    if (idx < N) sum += deg[idx];
  }
  part[t] = sum;
  __syncthreads();
  for (int off = 1; off < 1024; off <<= 1) {
    int val = (t >= off) ? part[t - off] : 0;
    __syncthreads();
    part[t] += val;
    __syncthreads();
  }
  int run = (t > 0) ? part[t - 1] : 0;
  for (int i = 0; i < chunk; ++i) {
    int idx = base + i;
    if (idx < N) {
      row_ptr[idx] = run;
      cursor[idx] = run;
      run += deg[idx];
    }
  }
  if (t == 1023) row_ptr[N] = part[1023];
}

__global__ void k_scatter(const int* __restrict__ esrc, const int* __restrict__ edst,
                          int* __restrict__ cursor, int* __restrict__ esrc_s,
                          int* __restrict__ edst_s, int E) {
  int e = blockIdx.x * 256 + threadIdx.x;
  if (e < E) {
    int d = edst[e];
    int p = atomicAdd(&cursor[d], 1);
    esrc_s[p] = esrc[e];
    edst_s[p] = d;
  }
}

// ---------------- fused MFMA edge kernel: wave = 32 consecutive CSR-sorted edges ----
// Round-16 winner configuration (WST=192, no setprio). Unchanged.
template <bool SZERO>
__global__ __launch_bounds__(128) void k_edge_mfma(
    const float* __restrict__ xcur, const float* __restrict__ s, const float* __restrict__ v,
    const int* __restrict__ esrc_s, const int* __restrict__ edst_s,
    const u16* __restrict__ fc1L, const float* __restrict__ b1,
    const u16* __restrict__ fc2L, const u16* __restrict__ WsvL0,
    const u16* __restrict__ WsvL1, const u16* __restrict__ WvsL0,
    const u16* __restrict__ WvsL1, float* __restrict__ aggbuf, int E) {
  __shared__ u16 wbAll[2][32 * WST];
  __shared__ float aAll[2][32][6];
  __shared__ int dAll[2][32];
  int wid = threadIdx.x >> 6, lane = threadIdx.x & 63;
  int e0 = (blockIdx.x * 2 + wid) * 32;
  if (e0 >= E) return;
  u16* wb = wbAll[wid];
  int lrow = lane & 15, lg = lane >> 4;

  // ====== geometry: lane = (el = lane>>1, qq = lane&1); one (edge, vec) per lane ======
  {
    int el = lane >> 1, qq = lane & 1;
    int ge = e0 + el;
    if (ge >= E) ge = E - 1;
    int gs = esrc_s[ge], gd = edst_s[ge];
    const float* ps = xcur + (size_t)gs * 6 + qq * 3;
    const float* pd = xcur + (size_t)gd * 6 + qq * 3;
    float vx = ps[0] - pd[0];
    float vy = ps[1] - pd[1];
    float vz = ps[2] - pd[2];
    float r2 = vx * vx + vy * vy + vz * vz;
    float rr = sqrtf(r2);
    float invr = 1.0f / rr;
    float th = (PI_F / 3.0f) * rr;
    float s1, c1;
    __sincosf(th, &s1, &c1);
    float twc = 2.0f * c1;
    float snm = 0.f, sn = s1;
    float fc = BESSEL_C * invr;
    float f8[8];
#pragma unroll
    for (int nn = 0; nn < 8; ++nn) {
      f8[nn] = fc * sn;
      float nx = twc * sn - snm;
      snm = sn;
      sn = nx;
    }
    float uu = (2.0f / 3.0f) * rr - 2.0f;
    float cut;
    if (uu > 0.f) cut = 0.f;
    else if (uu < -1.f) cut = 1.f;
    else cut = (1.0f - __cosf(PI_F * uu)) * 0.5f;
    float sc = cut * SQRT3 * invr;
    u32* fp = (u32*)(wb + FOFF + el * 40);
#pragma unroll
    for (int i = 0; i < 4; ++i) fp[qq * 4 + i] = pkbf(f8[2 * i], f8[2 * i + 1]);
#pragma unroll
    for (int i = 0; i < 4; ++i) fp[8 + qq * 4 + i] = 0u;
    float* ap = aAll[wid][el];
    ap[qq * 3 + 0] = vx * sc;
    ap[qq * 3 + 1] = vy * sc;
    ap[qq * 3 + 2] = vz * sc;
    if (qq == 0) dAll[wid][el] = gd;
  }
  lds_fence();

  // ====== MLP: hid[32][64] = silu(f @ fc1 + b1) via 8 MFMA (B shared across halves) ====
  {
    bf16x8 fA0 = *(const bf16x8*)(wb + FOFF + lrow * 40 + lg * 8);
    bf16x8 fA1 = *(const bf16x8*)(wb + FOFF + (16 + lrow) * 40 + lg * 8);
    f32x4 hp0[4], hp1[4];
#pragma unroll
    for (int nb = 0; nb < 4; ++nb) {
      bf16x8 bB = *(const bf16x8*)(fc1L + (size_t)(lg * 64 + nb * 16 + lrow) * 8);
      f32x4 z = {0.f, 0.f, 0.f, 0.f};
      hp0[nb] = mfma16(fA0, bB, z);
      hp1[nb] = mfma16(fA1, bB, z);
    }
#pragma unroll
    for (int nb = 0; nb < 4; ++nb) {
      float bias = b1[nb * 16 + lrow];
      int col = nb * 16 + lrow;
      {
        float hv[4];
#pragma unroll
        for (int r = 0; r < 4; ++r) {
          float xv = hp0[nb][r] + bias;
          hv[r] = xv * (1.0f / (1.0f + __expf(-xv)));
        }
        u32 p01 = pkbf(hv[0], hv[1]);
        u32 p23 = pkbf(hv[2], hv[3]);
        wb[(4 * lg + 0) * 72 + col] = (u16)p01;
        wb[(4 * lg + 1) * 72 + col] = (u16)(p01 >> 16);
        wb[(4 * lg + 2) * 72 + col] = (u16)p23;
        wb[(4 * lg + 3) * 72 + col] = (u16)(p23 >> 16);
      }
      {
        float hv[4];
#pragma unroll
        for (int r = 0; r < 4; ++r) {
          float xv = hp1[nb][r] + bias;
          hv[r] = xv * (1.0f / (1.0f + __expf(-xv)));
        }
        u32 p01 = pkbf(hv[0], hv[1]);
        u32 p23 = pkbf(hv[2], hv[3]);
        wb[(16 + 4 * lg + 0) * 72 + col] = (u16)p01;
        wb[(16 + 4 * lg + 1) * 72 + col] = (u16)(p01 >> 16);
        wb[(16 + 4 * lg + 2) * 72 + col] = (u16)p23;
        wb[(16 + 4 * lg + 3) * 72 + col] = (u16)(p23 >> 16);
      }
    }
  }
  lds_fence();

  // hid A-fragments (both halves)
  bf16x8 ha0 = *(const bf16x8*)(wb + lrow * 72 + lg * 8);
  bf16x8 hbf0 = *(const bf16x8*)(wb + lrow * 72 + 32 + lg * 8);
  bf16x8 ha1 = *(const bf16x8*)(wb + (16 + lrow) * 72 + lg * 8);
  bf16x8 hbf1 = *(const bf16x8*)(wb + (16 + lrow) * 72 + 32 + lg * 8);
  lds_fence();   // reads done before wb overwrite

  // ---- GEMM2: w[32,192] = hid @ fc2, B-frags shared across halves; swizzled store
  int xw = lg << 3;
#pragma unroll
  for (int nb = (SZERO ? 8 : 0); nb < 12; ++nb) {
    bf16x8 b0 = *(const bf16x8*)(fc2L + (size_t)(lg * 192 + nb * 16 + lrow) * 8);
    bf16x8 b1v = *(const bf16x8*)(fc2L + (size_t)((4 + lg) * 192 + nb * 16 + lrow) * 8);
    f32x4 z = {0.f, 0.f, 0.f, 0.f};
    f32x4 c0 = mfma16(ha0, b0, z);
    c0 = mfma16(hbf0, b1v, c0);
    f32x4 c1 = mfma16(ha1, b0, z);
    c1 = mfma16(hbf1, b1v, c1);
    int n = nb * 16 + lrow;
    int pn = (n < 128) ? ((n & 1) * 64 + (n >> 1)) : (128 + (n & 1) * 32 + ((n - 128) >> 1));
    int cx = pn ^ xw;
    {
      int rb = (4 * lg) * WST + cx;
      u32 p01 = pkbf(c0[0], c0[1]);
      u32 p23 = pkbf(c0[2], c0[3]);
      wb[rb] = (u16)p01;
      wb[rb + WST] = (u16)(p01 >> 16);
      wb[rb + 2 * WST] = (u16)p23;
      wb[rb + 3 * WST] = (u16)(p23 >> 16);
    }
    {
      int rb = (16 + 4 * lg) * WST + cx;
      u32 p01 = pkbf(c1[0], c1[1]);
      u32 p23 = pkbf(c1[2], c1[3]);
      wb[rb] = (u16)p01;
      wb[rb + WST] = (u16)(p01 >> 16);
      wb[rb + 2 * WST] = (u16)p23;
      wb[rb + 3 * WST] = (u16)(p23 >> 16);
    }
  }
  lds_fence();

  // swizzled row pointers (offsets used below are multiples of 32 -> swizzle-safe)
  const u16* wrow0 = wb + lrow * WST + (((lg ^ (lrow >> 2)) & 3) << 3);
  const u16* wrow1 = wrow0 + 16 * WST;

  int prow0 = e0 + lrow;
  if (prow0 >= E) prow0 = E - 1;
  int prow1 = e0 + 16 + lrow;
  if (prow1 >= E) prow1 = E - 1;
  int srcs[2] = {esrc_s[prow0], esrc_s[prow1]};

  // ---- Q path: T = s_src (.) w1 ; Q = T @ W_sv (B-frags shared across halves)
  f32x4 q0[2][2], q1[2][2];
  if (!SZERO) {
    U8 t0a[2], t0b[2], t1a[2], t1b[2];
#pragma unroll
    for (int h = 0; h < 2; ++h) {
      const u16* wr = h ? wrow1 : wrow0;
      const float* sp = s + (size_t)srcs[h] * 64;
      float sv0[8], sv1[8];
      *(f32x4*)(sv0) = *(const f32x4*)(sp + lg * 8);
      *(f32x4*)(sv0 + 4) = *(const f32x4*)(sp + lg * 8 + 4);
      *(f32x4*)(sv1) = *(const f32x4*)(sp + 32 + lg * 8);
      *(f32x4*)(sv1 + 4) = *(const f32x4*)(sp + 32 + lg * 8 + 4);
      i32x4 W0a = *(const i32x4*)(wr);
      i32x4 W0b = *(const i32x4*)(wr + 32);
      i32x4 W1a = *(const i32x4*)(wr + 64);
      i32x4 W1b = *(const i32x4*)(wr + 96);
#pragma unroll
      for (int j2 = 0; j2 < 4; ++j2) {
        u32 wa = (u32)W0a[j2], wbv = (u32)W0b[j2], wc = (u32)W1a[j2], wd = (u32)W1b[j2];
        t0a[h].w[j2] = pkbf(sv0[2 * j2] * blo(wa), sv0[2 * j2 + 1] * bhi(wa));
        t0b[h].w[j2] = pkbf(sv1[2 * j2] * blo(wbv), sv1[2 * j2 + 1] * bhi(wbv));
        t1a[h].w[j2] = pkbf(sv0[2 * j2] * blo(wc), sv0[2 * j2 + 1] * bhi(wc));
        t1b[h].w[j2] = pkbf(sv1[2 * j2] * blo(wd), sv1[2 * j2 + 1] * bhi(wd));
      }
    }
#pragma unroll
    for (int nb = 0; nb < 2; ++nb) {
      bf16x8 bA = *(const bf16x8*)(WsvL0 + (size_t)(lg * 32 + nb * 16 + lrow) * 8);
      bf16x8 bB = *(const bf16x8*)(WsvL0 + (size_t)((4 + lg) * 32 + nb * 16 + lrow) * 8);
      bf16x8 bC = *(const bf16x8*)(WsvL1 + (size_t)(lg * 32 + nb * 16 + lrow) * 8);
      bf16x8 bD = *(const bf16x8*)(WsvL1 + (size_t)((4 + lg) * 32 + nb * 16 + lrow) * 8);
#pragma unroll
      for (int h = 0; h < 2; ++h) {
        f32x4 z = {0.f, 0.f, 0.f, 0.f};
        f32x4 c = mfma16(t0a[h].v, bA, z);
        c = mfma16(t0b[h].v, bB, c);
        q0[h][nb] = c;
        f32x4 c2 = mfma16(t1a[h].v, bC, z);
        c2 = mfma16(t1b[h].v, bD, c2);
        q1[h][nb] = c2;
      }
    }
  }

  // ---- M path: G = (v_src . a) (.) w2 ; msg_s = G @ Wvs (B-frags shared)
  U8 ga[2], gb[2];
#pragma unroll
  for (int h = 0; h < 2; ++h) {
    const float* ap = aAll[wid][h * 16 + lrow];
    float a00 = ap[0], a01 = ap[1], a02 = ap[2], a10 = ap[3], a11 = ap[4], a12 = ap[5];
    float vl[24];
    const float* vp = v + (size_t)srcs[h] * 96 + lg * 24;
#pragma unroll
    for (int i = 0; i < 6; ++i) *(f32x4*)(vl + 4 * i) = *(const f32x4*)(vp + 4 * i);
    const u16* wr = h ? wrow1 : wrow0;
    i32x4 W2a = *(const i32x4*)(wr + 128);
    i32x4 W2b = *(const i32x4*)(wr + 160);
#pragma unroll
    for (int j2 = 0; j2 < 4; ++j2) {
      float d0a, d1a, d0b, d1b;
      {
        float vx = vl[6 * j2 + 0], vy = vl[6 * j2 + 1], vz = vl[6 * j2 + 2];
        d0a = vx * a00 + vy * a01 + vz * a02;
        d1a = vx * a10 + vy * a11 + vz * a12;
      }
      {
        float vx = vl[6 * j2 + 3], vy = vl[6 * j2 + 4], vz = vl[6 * j2 + 5];
        d0b = vx * a00 + vy * a01 + vz * a02;
        d1b = vx * a10 + vy * a11 + vz * a12;
      }
      u32 wa = (u32)W2a[j2], wbv = (u32)W2b[j2];
      ga[h].w[j2] = pkbf(d0a * blo(wa), d0b * bhi(wa));
      gb[h].w[j2] = pkbf(d1a * blo(wbv), d1b * bhi(wbv));
    }
  }
  f32x4 mS[2][6];
#pragma unroll
  for (int nb = 0; nb < 6; ++nb) {
    bf16x8 b0 = *(const bf16x8*)(WvsL0 + (size_t)(lg * 96 + nb * 16 + lrow) * 8);
    bf16x8 b1v = *(const bf16x8*)(WvsL1 + (size_t)(lg * 96 + nb * 16 + lrow) * 8);
#pragma unroll
    for (int h = 0; h < 2; ++h) {
      f32x4 z = {0.f, 0.f, 0.f, 0.f};
      f32x4 c = mfma16(ga[h].v, b0, z);
      c = mfma16(gb[h].v, b1v, c);
      mS[h][nb] = c;
    }
  }

  // ---- stage final msg rows into wb (overwrite w; swizzled)
  lds_fence();
#pragma unroll
  for (int h = 0; h < 2; ++h) {
    int rbase = (h * 16 + 4 * lg) * WST;
#pragma unroll
    for (int nb = 0; nb < 6; ++nb) {
      u32 p01 = pkbf(mS[h][nb][0], mS[h][nb][1]);
      u32 p23 = pkbf(mS[h][nb][2], mS[h][nb][3]);
      int colx = (nb * 16 + lrow) ^ xw;
      wb[rbase + colx] = (u16)p01;
      wb[rbase + WST + colx] = (u16)(p01 >> 16);
      wb[rbase + 2 * WST + colx] = (u16)p23;
      wb[rbase + 3 * WST + colx] = (u16)(p23 >> 16);
    }
    if (!SZERO) {
#pragma unroll
      for (int nb = 0; nb < 2; ++nb) {
#pragma unroll
        for (int r = 0; r < 4; ++r) {
          int el = h * 16 + 4 * lg + r;
          const float* ap = aAll[wid][el];
          float Q0v = q0[h][nb][r], Q1v = q1[h][nb][r];
          float v0 = Q0v * ap[0] + Q1v * ap[3];
          float v1 = Q0v * ap[1] + Q1v * ap[4];
          float v2 = Q0v * ap[2] + Q1v * ap[5];
          u32 p01 = pkbf(v0, v1);
          int base = el * WST + ((96 + nb * 16 + lrow) ^ xw);
          wb[base] = (u16)p01;
          wb[base + 32] = (u16)(p01 >> 16);
          wb[base + 64] = f2b(v2);
        }
      }
    }
  }
  lds_fence();

  // ---- segmented reduction over dst runs (edges sorted by dst) + atomicAdd ----
  {
    int nrows = E - e0;
    if (nrows > 32) nrows = 32;
    const int* dstv = dAll[wid];
    int c0 = lane, c1 = lane + 64, c2 = lane + 128;
    bool v1ok = SZERO ? (c1 < 96) : true;
    bool v2ok = SZERO ? false : true;
    float acc0 = 0.f, acc1 = 0.f, acc2 = 0.f;
    int prev = dstv[0];
    for (int r = 0; r < nrows; ++r) {
      int d = dstv[r];
      if (d != prev) {   // wave-uniform branch
        float* ab = aggbuf + (size_t)prev * 192;
        atomicAdd(ab + c0, acc0);
        if (v1ok) atomicAdd(ab + c1, acc1);
        if (v2ok) atomicAdd(ab + c2, acc2);
        acc0 = acc1 = acc2 = 0.f;
        prev = d;
      }
      int xo = ((r >> 2) & 3) << 3;
      int rb = r * WST;
      acc0 += b2f(wb[rb + (c0 ^ xo)]);
      if (v1ok) acc1 += b2f(wb[rb + (c1 ^ xo)]);
      if (v2ok) acc2 += b2f(wb[rb + (c2 ^ xo)]);
    }
    float* ab = aggbuf + (size_t)prev * 192;
    atomicAdd(ab + c0, acc0);
    if (v1ok) atomicAdd(ab + c1, acc1);
    if (v2ok) atomicAdd(ab + c2, acc2);
  }
}

// ---------------- node update (2 nodes per 256-thread block; reads dense agg) ------
template <bool ZERO_AGG>
__global__ __launch_bounds__(256) void k_gnode(
    float* __restrict__ aggbuf,
    float* __restrict__ s, float* __restrict__ sold, float* __restrict__ v,
    float* __restrict__ vold,
    const float* __restrict__ Amat, const float* __restrict__ Bmat,
    const float* __restrict__ Ws, const float* __restrict__ Wv,
    const float* __restrict__ Wproj, const int* __restrict__ nattr,
    const float* __restrict__ hArr, const float* __restrict__ mixArr, int layer,
    float* __restrict__ xout, int N) {
  int half = threadIdx.x >> 7;
  int t = threadIdx.x & 127;
  int n = blockIdx.x * 2 + half;
  bool active = n < N;
  if (!active) n = N - 1;
  __shared__ float agg[2][192];
  __shared__ float srow[2][64];
  __shared__ float vrow[2][96];
  __shared__ float gateS[2][32];
  __shared__ float vnewS[2][96];
  if (t < 96) {
    agg[half][t] = aggbuf[(size_t)n * 192 + t] * INV_SQRT_NN;
    agg[half][96 + t] = aggbuf[(size_t)n * 192 + 96 + t] * INV_SQRT_NN;
    if (ZERO_AGG && active) {
      aggbuf[(size_t)n * 192 + t] = 0.f;
      aggbuf[(size_t)n * 192 + 96 + t] = 0.f;
    }
  }
  if (t < 64) srow[half][t] = s[(size_t)n * 64 + t];
  if (t < 96) vrow[half][t] = v[(size_t)n * 96 + t];
  __syncthreads();
  int type = nattr[n];
  float hv = hArr[layer];
  float h2v = hv * hv;
  float mx = mixArr[layer];
  float cs = 0.f;
  if (t < 96) {
    cs = agg[half][t];
    const float* Ac = Amat + (size_t)type * 64 * 96 + t;
#pragma unroll 8
    for (int u = 0; u < 64; ++u) cs += srow[half][u] * Ac[u * 96];
  }
  if (t >= 64 && t < 96) gateS[half][t - 64] = 1.0f / (1.0f + __expf(-cs));
  __syncthreads();
  if (t < 64) {
    float gs = cs * (1.0f / (1.0f + __expf(-cs)));
    float sis = 0.f;
#pragma unroll 8
    for (int u = 0; u < 64; ++u) sis += srow[half][u] * Ws[u * 64 + t];
    float scur = srow[half][t];
    float sprev = sold[(size_t)n * 64 + t];
    float snew = 2.f * scur - sprev + h2v * (mx * gs + (mx - 1.f) * sis);
    if (active) {
      sold[(size_t)n * 64 + t] = scur;
      s[(size_t)n * 64 + t] = snew;
    }
  }
  if (t < 96) {
    int vch = t / 3, c = t - vch * 3;
    float cv = agg[half][96 + c * 32 + vch];
    const float* Bc = Bmat + (size_t)type * 1024 + vch;
    float scv = 0.f, siv = 0.f;
#pragma unroll 8
    for (int u = 0; u < 32; ++u) {
      float vu = vrow[half][u * 3 + c];
      scv += vu * Bc[u * 32];
      siv += vu * Wv[u * 32 + vch];
    }
    cv += scv;
    float gv = cv * gateS[half][vch];
    float vcur = vrow[half][t];
    float vprev = vold[(size_t)n * 96 + t];
    float vnew = 2.f * vcur - vprev + h2v * (mx * gv + (mx - 1.f) * siv);
    if (active) {
      vold[(size_t)n * 96 + t] = vcur;
      v[(size_t)n * 96 + t] = vnew;
    }
    vnewS[half][t] = vnew;
  }
  __syncthreads();
  if (t < 6 && active) {
    int i = t / 3, c = t - i * 3;
    float acc = 0.f;
#pragma unroll
    for (int vo = 0; vo < 32; ++vo) acc += vnewS[half][vo * 3 + c] * Wproj[vo * 2 + i];
    xout[(size_t)n * 6 + t] = acc;
  }
}

extern "C" void kernel_launch(void* const* d_in, const int* in_sizes, int n_in,
                              void* d_out, int out_size, void* d_ws, size_t ws_size,
                              hipStream_t stream) {
  const float* x = (const float*)d_in[0];
  const float* emb = (const float*)d_in[1];
  const float* Wup = (const float*)d_in[2];
  const float* Wproj = (const float*)d_in[3];
  const float* fc1 = (const float*)d_in[4];
  const float* b1 = (const float*)d_in[5];
  const float* fc2 = (const float*)d_in[6];
  const float* Wsv = (const float*)d_in[7];
  const float* Wvs = (const float*)d_in[8];
  const float* Wscs = (const float*)d_in[9];
  const float* Wscv = (const float*)d_in[10];
  const float* Ws = (const float*)d_in[11];
  const float* Wv = (const float*)d_in[12];
  const float* hArr = (const float*)d_in[13];
  const float* mixArr = (const float*)d_in[14];
  const int* nattr = (const int*)d_in[15];
  const int* esrc = (const int*)d_in[16];
  const int* edst = (const int*)d_in[17];

  const int N = in_sizes[0] / 6;
  const int E = in_sizes[16];

  float* ws = (float*)d_ws;
  size_t off = 0;
  auto alloc = [&](size_t nf) {
    float* p = ws + off;
    off += (nf + 3) & ~(size_t)3;
    return p;
  };
  float* sbuf = alloc((size_t)N * 64);
  float* sold = alloc((size_t)N * 64);
  float* vbuf = alloc((size_t)N * 96);
  float* vold = alloc((size_t)N * 96);
  float* xcur = alloc((size_t)N * 6);
  float* aggbuf = alloc((size_t)N * 192);
  float* Amat = alloc((size_t)cL * cNT * 64 * 96);
  float* Bmat = alloc((size_t)cL * cNT * 32 * 32);
  u16* fc2L = (u16*)alloc((size_t)cL * 6144);       // L*12288 bf16
  u16* WsvL = (u16*)alloc((size_t)cL * 2048);       // L*2*2048 bf16
  u16* WvsL = (u16*)alloc((size_t)cL * 3072);       // L*2*3072 bf16
  u16* fc1L = (u16*)alloc((size_t)cL * 1024);       // L*2048 bf16 (kq padded to 4)
  int* deg = (int*)alloc((size_t)(N + 4));
  int* row_ptr = (int*)alloc((size_t)(N + 4));
  int* cursor = (int*)alloc((size_t)(N + 4));
  int* esrc_s = (int*)alloc((size_t)E);
  int* edst_s = (int*)alloc((size_t)E);

  // init
  hipMemsetAsync(sbuf, 0, sizeof(float) * (size_t)N * 128, stream);   // sbuf + sold
  hipMemsetAsync(aggbuf, 0, sizeof(float) * (size_t)N * 192, stream); // layer-0 agg
  hipMemsetAsync(deg, 0, sizeof(int) * (size_t)N, stream);
  k_init<<<(N * 32 + 255) / 256, 256, 0, stream>>>(x, Wup, vbuf, vold, xcur, N);
  {
    int tot = cL * cNT * 64 * 96 + cL * cNT * 32 * 32 +
              cL * 12288 + cL * 4096 + cL * 6144 + cL * 2048;
    k_prep<<<(tot + 255) / 256, 256, 0, stream>>>(emb, Wscs, Wscv, fc2, Wsv, Wvs, fc1,
                                                  Amat, Bmat, fc2L, WsvL, WvsL, fc1L);
  }
  k_hist<<<(E + 255) / 256, 256, 0, stream>>>(edst, deg, E);
  k_scan<<<1, 1024, 0, stream>>>(deg, row_ptr, cursor, N);
  k_scatter<<<(E + 255) / 256, 256, 0, stream>>>(esrc, edst, cursor, esrc_s, edst_s, E);

  int eblocks = (E + 63) / 64;
  int gblocks = (N + 1) / 2;
  for (int l = 0; l < cL; ++l) {
    if (l == 0)
      k_edge_mfma<true><<<eblocks, 128, 0, stream>>>(
          xcur, sbuf, vbuf, esrc_s, edst_s, fc1L + l * 2048, b1 + l * 64,
          fc2L + l * 12288, WsvL + l * 4096, WsvL + l * 4096 + 2048,
          WvsL + l * 6144, WvsL + l * 6144 + 3072, aggbuf, E);
    else
      k_edge_mfma<false><<<eblocks, 128, 0, stream>>>(
          xcur, sbuf, vbuf, esrc_s, edst_s, fc1L + l * 2048, b1 + l * 64,
          fc2L + l * 12288, WsvL + l * 4096, WsvL + l * 4096 + 2048,
          WvsL + l * 6144, WvsL + l * 6144 + 3072, aggbuf, E);
    float* xout = (l == cL - 1) ? (float*)d_out : xcur;
    if (l < cL - 1)
      k_gnode<true><<<gblocks, 256, 0, stream>>>(
          aggbuf, sbuf, sold, vbuf, vold, Amat + (size_t)l * cNT * 64 * 96,
          Bmat + (size_t)l * cNT * 1024, Ws + l * 4096, Wv + l * 1024, Wproj, nattr,
          hArr, mixArr, l, xout, N);
    else
      k_gnode<false><<<gblocks, 256, 0, stream>>>(
          aggbuf, sbuf, sold, vbuf, vold, Amat + (size_t)l * cNT * 64 * 96,
          Bmat + (size_t)l * cNT * 1024, Ws + l * 4096, Wv + l * 1024, Wproj, nattr,
          hArr, mixArr, l, xout, N);
  }
}